// Round 1
// 767.205 us; speedup vs baseline: 1.1837x; 1.1837x over previous
//
#include <hip/hip_runtime.h>
#include <hip/hip_bf16.h>

typedef short short8 __attribute__((ext_vector_type(8)));
typedef float floatx4 __attribute__((ext_vector_type(4)));

__device__ __forceinline__ short f2bf(float x) {
  __hip_bfloat16 h = __float2bfloat16(x);
  return __builtin_bit_cast(short, h);
}

// Load 8 consecutive elements at element index idx, as bf16 bits.
// f32=1: source is float32 (external inputs). f32=0: source is bf16 (internal).
__device__ __forceinline__ short8 load8(const void* __restrict__ p, size_t idx, int f32) {
  if (f32) {
    const float* f = (const float*)p + idx;
    short8 r;
#pragma unroll
    for (int i = 0; i < 8; i++) r[i] = f2bf(f[i]);
    return r;
  }
  return *(const short8*)((const short*)p + idx);
}

// C[m,n] = sum_k A[m,k] * B[n,k].  A: MxK (element offset aoff), B: NxK.
// omode 0: C bf16 row-major. 1: C bf16 scattered to vT layout
//   C[((m>>11)*1024 + n)*2048 + (m&2047)]. 2: C float32 row-major (d_out).
__global__ __launch_bounds__(256) void gemm_bt(
    const void* __restrict__ A,
    const void* __restrict__ Bm,
    void* __restrict__ C,
    int M, int N, int K, int omode,
    int af32, int bf32, unsigned long long aoff)
{
  __shared__ short As[64][72];  // 144 B stride: b128-aligned, 2-way bank alias only (free)
  __shared__ short Bs[64][72];
  const int tid  = threadIdx.x;
  const int wave = tid >> 6, lane = tid & 63;
  const int quad = lane >> 4, l15 = lane & 15;
  const int m0 = blockIdx.y * 64, n0 = blockIdx.x * 64;
  const int wr = (wave >> 1) * 32, wc = (wave & 1) * 32;

  floatx4 acc00 = {}, acc01 = {}, acc10 = {}, acc11 = {};

  const int r0 = tid >> 3, kc0 = (tid & 7) << 3;
  const int r1 = r0 + 32;

  for (int k0 = 0; k0 < K; k0 += 64) {
    __syncthreads();
    *(short8*)&As[r0][kc0] = load8(A, aoff + (size_t)(m0 + r0) * K + k0 + kc0, af32);
    *(short8*)&As[r1][kc0] = load8(A, aoff + (size_t)(m0 + r1) * K + k0 + kc0, af32);
    short8 bz = {};
    *(short8*)&Bs[r0][kc0] = (n0 + r0 < N) ? load8(Bm, (size_t)(n0 + r0) * K + k0 + kc0, bf32) : bz;
    *(short8*)&Bs[r1][kc0] = (n0 + r1 < N) ? load8(Bm, (size_t)(n0 + r1) * K + k0 + kc0, bf32) : bz;
    __syncthreads();
#pragma unroll
    for (int kk = 0; kk < 64; kk += 32) {
      short8 a0 = *(const short8*)&As[wr + l15][kk + quad * 8];
      short8 a1 = *(const short8*)&As[wr + 16 + l15][kk + quad * 8];
      short8 b0 = *(const short8*)&Bs[wc + l15][kk + quad * 8];
      short8 b1 = *(const short8*)&Bs[wc + 16 + l15][kk + quad * 8];
      acc00 = __builtin_amdgcn_mfma_f32_16x16x32_bf16(a0, b0, acc00, 0, 0, 0);
      acc01 = __builtin_amdgcn_mfma_f32_16x16x32_bf16(a0, b1, acc01, 0, 0, 0);
      acc10 = __builtin_amdgcn_mfma_f32_16x16x32_bf16(a1, b0, acc10, 0, 0, 0);
      acc11 = __builtin_amdgcn_mfma_f32_16x16x32_bf16(a1, b1, acc11, 0, 0, 0);
    }
  }

  floatx4 accs[2][2] = {{acc00, acc01}, {acc10, acc11}};
#pragma unroll
  for (int i = 0; i < 2; i++)
#pragma unroll
    for (int j = 0; j < 2; j++)
#pragma unroll
      for (int r = 0; r < 4; r++) {
        int row = m0 + wr + i * 16 + quad * 4 + r;   // C/D: row=(lane>>4)*4+reg
        int col = n0 + wc + j * 16 + l15;            //      col=lane&15
        if (col < N) {
          float v = accs[i][j][r];
          if (omode == 2) {
            ((float*)C)[(size_t)row * N + col] = v;            // fp32 final output
          } else if (omode == 1) {
            ((__hip_bfloat16*)C)[(((size_t)(row >> 11) * 1024 + col) << 11) + (row & 2047)] =
                __float2bfloat16(v);
          } else {
            ((__hip_bfloat16*)C)[(size_t)row * N + col] = __float2bfloat16(v);
          }
        }
      }
}

// In-place interleaved RoPE on internal bf16 buffers.
// ppp = pairs per position (256 for q_R, 16 for k_R). pos = (g/ppp) & 2047.
__global__ __launch_bounds__(256) void rope_kernel(__hip_bfloat16* p, int n_pairs, int ppp) {
  int g = blockIdx.x * 256 + threadIdx.x;
  if (g >= n_pairs) return;
  int i = g & 15;
  int pos = (g / ppp) & 2047;
  float inv_freq = powf(10000.0f, -(float)i * (1.0f / 16.0f));
  float ang = (float)pos * inv_freq;
  float sn, cs;
  sincosf(ang, &sn, &cs);
  float x1 = __bfloat162float(p[2 * g]);
  float x2 = __bfloat162float(p[2 * g + 1]);
  p[2 * g]     = __float2bfloat16(x1 * cs - x2 * sn);
  p[2 * g + 1] = __float2bfloat16(x1 * sn + x2 * cs);
}

// Batched causal flash attention. blockIdx.z = batch (constant strides applied
// in-kernel; launch with gridDim.z=1 and pre-offset pointers for b=0 behavior).
// qC:(S,H,64) qR:(S,H,32) kC:(S,H,64) kR:(S,32) vT:(H*64,S) -> O:(S,H*64)  (bf16)
__global__ __launch_bounds__(256) void mla_attn(
    const __hip_bfloat16* __restrict__ qC,
    const __hip_bfloat16* __restrict__ qR,
    const __hip_bfloat16* __restrict__ kC,
    const __hip_bfloat16* __restrict__ kR,
    const __hip_bfloat16* __restrict__ vT,
    __hip_bfloat16* __restrict__ O)
{
  const int tid  = threadIdx.x;
  const int wave = tid >> 6, lane = tid & 63;
  const int quad = lane >> 4, l15 = lane & 15;
  const int h = blockIdx.y;
  // Descending q0: longest (most k-tiles) blocks dispatch first.
  const int q0 = (gridDim.x - 1 - blockIdx.x) * 64;
  const int b = blockIdx.z;

  __shared__ short Ks[32][104];      // 32 keys x 96 dims (+8 pad)
  __shared__ short Vt[64][40];       // 64 dv x 32 keys (+8 pad)
  __shared__ short Ps[4][16][40];    // per-wave P round-trip (C->A layout)

  const short* qCs = reinterpret_cast<const short*>(qC) + (size_t)b * 2097152;
  const short* qRs = reinterpret_cast<const short*>(qR) + (size_t)b * 1048576;
  const short* kCs = reinterpret_cast<const short*>(kC) + (size_t)b * 2097152;
  const short* kRs = reinterpret_cast<const short*>(kR) + (size_t)b * 65536;
  const short* Vs  = reinterpret_cast<const short*>(vT) + (size_t)b * 2097152;
  __hip_bfloat16* Ob = O + (size_t)b * 2097152;

  // Q fragments (A-operand: m=lane&15, k=quad*8+j), loaded once
  const int qrow = q0 + wave * 16 + l15;
  const size_t qcbase = ((size_t)qrow * 16 + h) * 64;
  const size_t qrbase = ((size_t)qrow * 16 + h) * 32;
  short8 aq0 = *(const short8*)&qCs[qcbase + quad * 8];
  short8 aq1 = *(const short8*)&qCs[qcbase + 32 + quad * 8];
  short8 aq2 = *(const short8*)&qRs[qrbase + quad * 8];

  const float MASKV = -30000.0f;
  float mrow[4], lrow[4];
  floatx4 accO[4] = {};
#pragma unroll
  for (int r = 0; r < 4; r++) { mrow[r] = MASKV; lrow[r] = 0.f; }

  const float scale = 0.10206207261596575f;  // 1/sqrt(96)

  const int nkt = (q0 >> 5) + 2;
  for (int kt = 0; kt < nkt; kt++) {
    const int k0 = kt * 32;
    __syncthreads();
    // stage K: 32 keys x 96 dims = 384 vec8 chunks
    {
      int c = tid, key = c / 12, seg = c - key * 12;
      short8 kv;
      if (seg < 8) kv = *(const short8*)&kCs[((size_t)(k0 + key) * 16 + h) * 64 + seg * 8];
      else         kv = *(const short8*)&kRs[(size_t)(k0 + key) * 32 + (seg - 8) * 8];
      *(short8*)&Ks[key][seg * 8] = kv;
      if (tid < 128) {
        c = tid + 256; key = c / 12; seg = c - key * 12;
        short8 kv2;
        if (seg < 8) kv2 = *(const short8*)&kCs[((size_t)(k0 + key) * 16 + h) * 64 + seg * 8];
        else         kv2 = *(const short8*)&kRs[(size_t)(k0 + key) * 32 + (seg - 8) * 8];
        *(short8*)&Ks[key][seg * 8] = kv2;
      }
    }
    // stage V (pre-transposed): 64 dv x 32 keys
    {
      int dv = tid >> 2, kc = (tid & 3) << 3;
      short8 vv = *(const short8*)&Vs[((size_t)(h * 64 + dv)) * 2048 + k0 + kc];
      *(short8*)&Vt[dv][kc] = vv;
    }
    __syncthreads();

    float st[2][4];
#pragma unroll
    for (int j = 0; j < 2; j++) {
      short8 b0 = *(const short8*)&Ks[j * 16 + l15][quad * 8];
      short8 b1 = *(const short8*)&Ks[j * 16 + l15][32 + quad * 8];
      short8 b2 = *(const short8*)&Ks[j * 16 + l15][64 + quad * 8];
      floatx4 s = {};
      s = __builtin_amdgcn_mfma_f32_16x16x32_bf16(aq0, b0, s, 0, 0, 0);
      s = __builtin_amdgcn_mfma_f32_16x16x32_bf16(aq1, b1, s, 0, 0, 0);
      s = __builtin_amdgcn_mfma_f32_16x16x32_bf16(aq2, b2, s, 0, 0, 0);
      const int kpos = k0 + j * 16 + l15;
#pragma unroll
      for (int r = 0; r < 4; r++) {
        const int qpos = q0 + wave * 16 + quad * 4 + r;
        float t = fminf(fmaxf(s[r], -80.f), 80.f) * scale;  // clip BEFORE scale (ref order)
        st[j][r] = (kpos <= qpos) ? t : MASKV;
      }
    }
    float ps0[4], ps1[4], alpha[4];
#pragma unroll
    for (int r = 0; r < 4; r++) {
      float tm = fmaxf(st[0][r], st[1][r]);
      tm = fmaxf(tm, __shfl_xor(tm, 1));
      tm = fmaxf(tm, __shfl_xor(tm, 2));
      tm = fmaxf(tm, __shfl_xor(tm, 4));
      tm = fmaxf(tm, __shfl_xor(tm, 8));
      float mnew = fmaxf(mrow[r], tm);
      alpha[r] = __expf(mrow[r] - mnew);
      mrow[r] = mnew;
      float p0 = __expf(st[0][r] - mnew);
      float p1 = __expf(st[1][r] - mnew);
      ps0[r] = p0; ps1[r] = p1;
      float rs = p0 + p1;
      rs += __shfl_xor(rs, 1);
      rs += __shfl_xor(rs, 2);
      rs += __shfl_xor(rs, 4);
      rs += __shfl_xor(rs, 8);
      lrow[r] = lrow[r] * alpha[r] + rs;
    }
#pragma unroll
    for (int c = 0; c < 4; c++)
#pragma unroll
      for (int r = 0; r < 4; r++) accO[c][r] *= alpha[r];

    // P: C-layout -> LDS -> A-operand layout (per-wave private; same-wave DS order)
#pragma unroll
    for (int r = 0; r < 4; r++) {
      Ps[wave][quad * 4 + r][l15]      = f2bf(ps0[r]);
      Ps[wave][quad * 4 + r][16 + l15] = f2bf(ps1[r]);
    }
    short8 ap = *(const short8*)&Ps[wave][l15][quad * 8];
#pragma unroll
    for (int c = 0; c < 4; c++) {
      short8 bv = *(const short8*)&Vt[c * 16 + l15][quad * 8];
      accO[c] = __builtin_amdgcn_mfma_f32_16x16x32_bf16(ap, bv, accO[c], 0, 0, 0);
    }
  }

#pragma unroll
  for (int r = 0; r < 4; r++) {
    float inv = (lrow[r] > 0.f) ? 1.f / lrow[r] : 0.f;
    int s = q0 + wave * 16 + quad * 4 + r;
    size_t obase = (size_t)s * 1024 + h * 64;
#pragma unroll
    for (int c = 0; c < 4; c++)
      Ob[obase + c * 16 + l15] = __float2bfloat16(accO[c][r] * inv);
  }
}

extern "C" void kernel_launch(void* const* d_in, const int* in_sizes, int n_in,
                              void* d_out, int out_size, void* d_ws, size_t ws_size,
                              hipStream_t stream) {
  // Inputs are float32 (reference dtype); internal pipeline is bf16; output is float32.
  const void* x     = d_in[0];
  const void* W_DQ  = d_in[1];
  const void* W_UQ  = d_in[2];
  const void* W_QR  = d_in[3];
  const void* W_DKV = d_in[4];
  const void* W_UK  = d_in[5];
  const void* W_UV  = d_in[6];
  const void* W_KR  = d_in[7];
  const void* W_O   = d_in[8];
  float* out = (float*)d_out;
  __hip_bfloat16* ws = (__hip_bfloat16*)d_ws;

  dim3 blk(256);

  if (ws_size >= (size_t)76021760) {
    // ---------- big path: whole-problem GEMMs ----------
    __hip_bfloat16* cQ   = ws;                 // 8192x512
    __hip_bfloat16* cKV  = ws + 4194304;       // 8192x512
    __hip_bfloat16* attn = ws;                 // 8192x1024 (overlays dead cQ+cKV)
    __hip_bfloat16* qC   = ws + 8388608;       // (B,S,H,64)
    __hip_bfloat16* qR   = ws + 16777216;      // (B,S,H,32)
    __hip_bfloat16* kC   = ws + 20971520;      // (B,S,H,64)
    __hip_bfloat16* vT   = ws + 29360128;      // (B,1024,2048)
    __hip_bfloat16* kR   = ws + 37748736;      // (B,S,32)

    gemm_bt<<<dim3(8, 128), blk, 0, stream>>>(x,   W_DQ,  cQ,  8192, 512, 1024, 0, 1, 1, 0);
    gemm_bt<<<dim3(8, 128), blk, 0, stream>>>(x,   W_DKV, cKV, 8192, 512, 1024, 0, 1, 1, 0);
    gemm_bt<<<dim3(1, 128), blk, 0, stream>>>(x,   W_KR,  kR,  8192, 32, 1024, 0, 1, 1, 0);
    gemm_bt<<<dim3(16, 128), blk, 0, stream>>>(cQ,  W_UQ,  qC,  8192, 1024, 512, 0, 0, 1, 0);
    gemm_bt<<<dim3(8, 128), blk, 0, stream>>>(cQ,  W_QR,  qR,  8192, 512, 512, 0, 0, 1, 0);
    gemm_bt<<<dim3(16, 128), blk, 0, stream>>>(cKV, W_UK,  kC,  8192, 1024, 512, 0, 0, 1, 0);
    gemm_bt<<<dim3(16, 128), blk, 0, stream>>>(cKV, W_UV,  vT,  8192, 1024, 512, 1, 0, 1, 0);
    rope_kernel<<<dim3(8192), blk, 0, stream>>>(qR, 2097152, 256);
    rope_kernel<<<dim3(512), blk, 0, stream>>>(kR, 131072, 16);
    // Fused over batches: 2048 blocks -> 8 blocks/CU (LDS 16.9KB x 8 = 135KB,
    // VGPR 56 -> 8 waves/SIMD OK) = full 32-wave residency; causal tails of the
    // four batches overlap instead of serializing.
    mla_attn<<<dim3(32, 16, 4), blk, 0, stream>>>(qC, qR, kC, kR, vT, attn);
    gemm_bt<<<dim3(16, 128), blk, 0, stream>>>(attn, W_O, out, 8192, 1024, 1024, 2, 0, 1, 0);
  } else {
    // ---------- small path: per-batch arena (14.1 MB ws + d_out slice scratch) ----------
    __hip_bfloat16* qc = ws;                   // 2M el
    __hip_bfloat16* qr = ws + 2097152;         // 1M el
    __hip_bfloat16* kc = ws + 3145728;         // 2M el
    __hip_bfloat16* kr = ws + 5242880;         // 64K el
    __hip_bfloat16* F  = ws + 5308416;         // 2M el: cQ_b / cKV_b / attn_b

    for (int b = 0; b < 4; b++) {
      unsigned long long xoff = (unsigned long long)b * 2048 * 1024;
      float* outb = out + (size_t)b * 2097152;              // fp32 slice b
      __hip_bfloat16* vtb = (__hip_bfloat16*)outb;          // scratch inside the slice (dead before final)

      gemm_bt<<<dim3(8, 32), blk, 0, stream>>>(x, W_DQ,  F,  2048, 512, 1024, 0, 1, 1, xoff);
      gemm_bt<<<dim3(16, 32), blk, 0, stream>>>(F, W_UQ,  qc, 2048, 1024, 512, 0, 0, 1, 0);
      gemm_bt<<<dim3(8, 32), blk, 0, stream>>>(F, W_QR,  qr, 2048, 512, 512, 0, 0, 1, 0);
      gemm_bt<<<dim3(8, 32), blk, 0, stream>>>(x, W_DKV, F,  2048, 512, 1024, 0, 1, 1, xoff);
      gemm_bt<<<dim3(16, 32), blk, 0, stream>>>(F, W_UK,  kc, 2048, 1024, 512, 0, 0, 1, 0);
      gemm_bt<<<dim3(16, 32), blk, 0, stream>>>(F, W_UV,  vtb, 2048, 1024, 512, 1, 0, 1, 0);
      gemm_bt<<<dim3(1, 32), blk, 0, stream>>>(x, W_KR,  kr, 2048, 32, 1024, 0, 1, 1, xoff);
      rope_kernel<<<dim3(2048), blk, 0, stream>>>(qr, 524288, 256);
      rope_kernel<<<dim3(128), blk, 0, stream>>>(kr, 32768, 16);
      mla_attn<<<dim3(32, 16, 1), blk, 0, stream>>>(qc, qr, kc, kr, vtb, F);
      gemm_bt<<<dim3(16, 32), blk, 0, stream>>>(F, W_O, outb, 2048, 1024, 1024, 2, 0, 1, 0);
    }
  }
}

// Round 2
// 629.232 us; speedup vs baseline: 1.4433x; 1.2193x over previous
//
#include <hip/hip_runtime.h>
#include <hip/hip_bf16.h>

typedef short short8 __attribute__((ext_vector_type(8)));
typedef float floatx4 __attribute__((ext_vector_type(4)));

__device__ __forceinline__ short f2bf(float x) {
  __hip_bfloat16 h = __float2bfloat16(x);
  return __builtin_bit_cast(short, h);
}

// Load 8 consecutive elements at element index idx, as bf16 bits.
// f32=1: source is float32 (external inputs). f32=0: source is bf16 (internal).
__device__ __forceinline__ short8 load8(const void* __restrict__ p, size_t idx, int f32) {
  if (f32) {
    const float* f = (const float*)p + idx;
    short8 r;
#pragma unroll
    for (int i = 0; i < 8; i++) r[i] = f2bf(f[i]);
    return r;
  }
  return *(const short8*)((const short*)p + idx);
}

// C[m,n] = sum_k A[m,k] * B[n,k].  A: MxK (element offset aoff), B: NxK.
// omode 0: C bf16 row-major. 1: C bf16 scattered to vT layout
//   C[((m>>11)*1024 + n)*2048 + (m&2047)]. 2: C float32 row-major (d_out).
__global__ __launch_bounds__(256) void gemm_bt(
    const void* __restrict__ A,
    const void* __restrict__ Bm,
    void* __restrict__ C,
    int M, int N, int K, int omode,
    int af32, int bf32, unsigned long long aoff)
{
  __shared__ short As[64][72];  // 144 B stride: b128-aligned, 2-way bank alias only (free)
  __shared__ short Bs[64][72];
  const int tid  = threadIdx.x;
  const int wave = tid >> 6, lane = tid & 63;
  const int quad = lane >> 4, l15 = lane & 15;
  const int m0 = blockIdx.y * 64, n0 = blockIdx.x * 64;
  const int wr = (wave >> 1) * 32, wc = (wave & 1) * 32;

  floatx4 acc00 = {}, acc01 = {}, acc10 = {}, acc11 = {};

  const int r0 = tid >> 3, kc0 = (tid & 7) << 3;
  const int r1 = r0 + 32;

  for (int k0 = 0; k0 < K; k0 += 64) {
    __syncthreads();
    *(short8*)&As[r0][kc0] = load8(A, aoff + (size_t)(m0 + r0) * K + k0 + kc0, af32);
    *(short8*)&As[r1][kc0] = load8(A, aoff + (size_t)(m0 + r1) * K + k0 + kc0, af32);
    short8 bz = {};
    *(short8*)&Bs[r0][kc0] = (n0 + r0 < N) ? load8(Bm, (size_t)(n0 + r0) * K + k0 + kc0, bf32) : bz;
    *(short8*)&Bs[r1][kc0] = (n0 + r1 < N) ? load8(Bm, (size_t)(n0 + r1) * K + k0 + kc0, bf32) : bz;
    __syncthreads();
#pragma unroll
    for (int kk = 0; kk < 64; kk += 32) {
      short8 a0 = *(const short8*)&As[wr + l15][kk + quad * 8];
      short8 a1 = *(const short8*)&As[wr + 16 + l15][kk + quad * 8];
      short8 b0 = *(const short8*)&Bs[wc + l15][kk + quad * 8];
      short8 b1 = *(const short8*)&Bs[wc + 16 + l15][kk + quad * 8];
      acc00 = __builtin_amdgcn_mfma_f32_16x16x32_bf16(a0, b0, acc00, 0, 0, 0);
      acc01 = __builtin_amdgcn_mfma_f32_16x16x32_bf16(a0, b1, acc01, 0, 0, 0);
      acc10 = __builtin_amdgcn_mfma_f32_16x16x32_bf16(a1, b0, acc10, 0, 0, 0);
      acc11 = __builtin_amdgcn_mfma_f32_16x16x32_bf16(a1, b1, acc11, 0, 0, 0);
    }
  }

  floatx4 accs[2][2] = {{acc00, acc01}, {acc10, acc11}};
#pragma unroll
  for (int i = 0; i < 2; i++)
#pragma unroll
    for (int j = 0; j < 2; j++)
#pragma unroll
      for (int r = 0; r < 4; r++) {
        int row = m0 + wr + i * 16 + quad * 4 + r;   // C/D: row=(lane>>4)*4+reg
        int col = n0 + wc + j * 16 + l15;            //      col=lane&15
        if (col < N) {
          float v = accs[i][j][r];
          if (omode == 2) {
            ((float*)C)[(size_t)row * N + col] = v;            // fp32 final output
          } else if (omode == 1) {
            ((__hip_bfloat16*)C)[(((size_t)(row >> 11) * 1024 + col) << 11) + (row & 2047)] =
                __float2bfloat16(v);
          } else {
            ((__hip_bfloat16*)C)[(size_t)row * N + col] = __float2bfloat16(v);
          }
        }
      }
}

// In-place interleaved RoPE on internal bf16 buffers.
// ppp = pairs per position (256 for q_R, 16 for k_R). pos = (g/ppp) & 2047.
__global__ __launch_bounds__(256) void rope_kernel(__hip_bfloat16* p, int n_pairs, int ppp) {
  int g = blockIdx.x * 256 + threadIdx.x;
  if (g >= n_pairs) return;
  int i = g & 15;
  int pos = (g / ppp) & 2047;
  float inv_freq = powf(10000.0f, -(float)i * (1.0f / 16.0f));
  float ang = (float)pos * inv_freq;
  float sn, cs;
  sincosf(ang, &sn, &cs);
  float x1 = __bfloat162float(p[2 * g]);
  float x2 = __bfloat162float(p[2 * g + 1]);
  p[2 * g]     = __float2bfloat16(x1 * cs - x2 * sn);
  p[2 * g + 1] = __float2bfloat16(x1 * sn + x2 * cs);
}

// Batched causal flash attention, KVBLK=64.
// qC:(S,H,64) qR:(S,H,32) kC:(S,H,64) kR:(S,32) vT:(H*64,S) -> O:(S,H*64)  (bf16)
__global__ __launch_bounds__(256) void mla_attn(
    const __hip_bfloat16* __restrict__ qC,
    const __hip_bfloat16* __restrict__ qR,
    const __hip_bfloat16* __restrict__ kC,
    const __hip_bfloat16* __restrict__ kR,
    const __hip_bfloat16* __restrict__ vT,
    __hip_bfloat16* __restrict__ O)
{
  const int tid  = threadIdx.x;
  const int wave = tid >> 6, lane = tid & 63;
  const int quad = lane >> 4, l15 = lane & 15;
  const int h = blockIdx.y;
  // Descending q0: longest (most k-tiles) blocks dispatch first.
  const int q0 = (gridDim.x - 1 - blockIdx.x) * 64;
  const int b = blockIdx.z;

  __shared__ short Ks[64][104];      // 64 keys x 96 dims (+8 pad); 208B stride -> 2-way only
  __shared__ short Vt[64][72];       // 64 dv x 64 keys (+8 pad); 144B stride -> 2-way only
  __shared__ short Ps[4][16][76];    // per-wave P round-trip; 152B stride -> all quads distinct banks

  const short* qCs = reinterpret_cast<const short*>(qC) + (size_t)b * 2097152;
  const short* qRs = reinterpret_cast<const short*>(qR) + (size_t)b * 1048576;
  const short* kCs = reinterpret_cast<const short*>(kC) + (size_t)b * 2097152;
  const short* kRs = reinterpret_cast<const short*>(kR) + (size_t)b * 65536;
  const short* Vs  = reinterpret_cast<const short*>(vT) + (size_t)b * 2097152;
  __hip_bfloat16* Ob = O + (size_t)b * 2097152;

  // Q fragments (A-operand: m=lane&15, k=quad*8+j), loaded once
  const int qrow = q0 + wave * 16 + l15;
  const size_t qcbase = ((size_t)qrow * 16 + h) * 64;
  const size_t qrbase = ((size_t)qrow * 16 + h) * 32;
  short8 aq0 = *(const short8*)&qCs[qcbase + quad * 8];
  short8 aq1 = *(const short8*)&qCs[qcbase + 32 + quad * 8];
  short8 aq2 = *(const short8*)&qRs[qrbase + quad * 8];

  const float MASKV = -30000.0f;
  float mrow[4], lrow[4];               // lrow = PER-LANE partial sum (reduced after loop)
  floatx4 accO[4] = {};
#pragma unroll
  for (int r = 0; r < 4; r++) { mrow[r] = MASKV; lrow[r] = 0.f; }

  const float scale = 0.10206207261596575f;  // 1/sqrt(96)

  const int nkt = (q0 >> 6) + 1;
  for (int kt = 0; kt < nkt; kt++) {
    const int k0 = kt * 64;
    __syncthreads();
    // stage K: 64 keys x 96 dims = 768 vec8 chunks, 3 per thread
    {
#pragma unroll
      for (int it = 0; it < 3; it++) {
        int c = tid + it * 256;
        int key = c / 12, seg = c - key * 12;
        short8 kv;
        if (seg < 8) kv = *(const short8*)&kCs[((size_t)(k0 + key) * 16 + h) * 64 + seg * 8];
        else         kv = *(const short8*)&kRs[(size_t)(k0 + key) * 32 + (seg - 8) * 8];
        *(short8*)&Ks[key][seg * 8] = kv;
      }
    }
    // stage V (pre-transposed): 64 dv x 64 keys = 512 chunks, 2 per thread
    {
#pragma unroll
      for (int it = 0; it < 2; it++) {
        int c = tid + it * 256;
        int dv = c >> 3, kc = (c & 7) << 3;
        short8 vv = *(const short8*)&Vs[((size_t)(h * 64 + dv)) * 2048 + k0 + kc];
        *(short8*)&Vt[dv][kc] = vv;
      }
    }
    __syncthreads();

    float st[4][4];
    __builtin_amdgcn_s_setprio(1);
#pragma unroll
    for (int j = 0; j < 4; j++) {
      short8 b0 = *(const short8*)&Ks[j * 16 + l15][quad * 8];
      short8 b1 = *(const short8*)&Ks[j * 16 + l15][32 + quad * 8];
      short8 b2 = *(const short8*)&Ks[j * 16 + l15][64 + quad * 8];
      floatx4 s = {};
      s = __builtin_amdgcn_mfma_f32_16x16x32_bf16(aq0, b0, s, 0, 0, 0);
      s = __builtin_amdgcn_mfma_f32_16x16x32_bf16(aq1, b1, s, 0, 0, 0);
      s = __builtin_amdgcn_mfma_f32_16x16x32_bf16(aq2, b2, s, 0, 0, 0);
      const int kpos = k0 + j * 16 + l15;
#pragma unroll
      for (int r = 0; r < 4; r++) {
        const int qpos = q0 + wave * 16 + quad * 4 + r;
        float t = fminf(fmaxf(s[r], -80.f), 80.f) * scale;  // clip BEFORE scale (ref order)
        st[j][r] = (kpos <= qpos) ? t : MASKV;
      }
    }
    __builtin_amdgcn_s_setprio(0);

    float ps[4][4], alpha[4];
#pragma unroll
    for (int r = 0; r < 4; r++) {
      float tm = fmaxf(fmaxf(st[0][r], st[1][r]), fmaxf(st[2][r], st[3][r]));
      tm = fmaxf(tm, __shfl_xor(tm, 1));
      tm = fmaxf(tm, __shfl_xor(tm, 2));
      tm = fmaxf(tm, __shfl_xor(tm, 4));
      tm = fmaxf(tm, __shfl_xor(tm, 8));
      float mnew = fmaxf(mrow[r], tm);
      alpha[r] = __expf(mrow[r] - mnew);
      mrow[r] = mnew;
      float rs = 0.f;
#pragma unroll
      for (int j = 0; j < 4; j++) {
        float p = __expf(st[j][r] - mnew);
        ps[j][r] = p;
        rs += p;
      }
      lrow[r] = lrow[r] * alpha[r] + rs;   // per-lane partial; cross-lane reduce deferred
    }
#pragma unroll
    for (int c = 0; c < 4; c++)
#pragma unroll
      for (int r = 0; r < 4; r++) accO[c][r] *= alpha[r];

    // P: C-layout -> LDS -> A-operand layout (per-wave private; same-wave DS order)
#pragma unroll
    for (int j = 0; j < 4; j++)
#pragma unroll
      for (int r = 0; r < 4; r++)
        Ps[wave][quad * 4 + r][j * 16 + l15] = f2bf(ps[j][r]);
    short8 ap0 = *(const short8*)&Ps[wave][l15][quad * 8];
    short8 ap1 = *(const short8*)&Ps[wave][l15][32 + quad * 8];
    __builtin_amdgcn_s_setprio(1);
#pragma unroll
    for (int c = 0; c < 4; c++) {
      short8 bv0 = *(const short8*)&Vt[c * 16 + l15][quad * 8];
      short8 bv1 = *(const short8*)&Vt[c * 16 + l15][32 + quad * 8];
      accO[c] = __builtin_amdgcn_mfma_f32_16x16x32_bf16(ap0, bv0, accO[c], 0, 0, 0);
      accO[c] = __builtin_amdgcn_mfma_f32_16x16x32_bf16(ap1, bv1, accO[c], 0, 0, 0);
    }
    __builtin_amdgcn_s_setprio(0);
  }

#pragma unroll
  for (int r = 0; r < 4; r++) {
    float rs = lrow[r];
    rs += __shfl_xor(rs, 1);
    rs += __shfl_xor(rs, 2);
    rs += __shfl_xor(rs, 4);
    rs += __shfl_xor(rs, 8);
    float inv = (rs > 0.f) ? 1.f / rs : 0.f;
    int s = q0 + wave * 16 + quad * 4 + r;
    size_t obase = (size_t)s * 1024 + h * 64;
#pragma unroll
    for (int c = 0; c < 4; c++)
      Ob[obase + c * 16 + l15] = __float2bfloat16(accO[c][r] * inv);
  }
}

extern "C" void kernel_launch(void* const* d_in, const int* in_sizes, int n_in,
                              void* d_out, int out_size, void* d_ws, size_t ws_size,
                              hipStream_t stream) {
  // Inputs are float32 (reference dtype); internal pipeline is bf16; output is float32.
  const void* x     = d_in[0];
  const void* W_DQ  = d_in[1];
  const void* W_UQ  = d_in[2];
  const void* W_QR  = d_in[3];
  const void* W_DKV = d_in[4];
  const void* W_UK  = d_in[5];
  const void* W_UV  = d_in[6];
  const void* W_KR  = d_in[7];
  const void* W_O   = d_in[8];
  float* out = (float*)d_out;
  __hip_bfloat16* ws = (__hip_bfloat16*)d_ws;

  dim3 blk(256);

  if (ws_size >= (size_t)76021760) {
    // ---------- big path: whole-problem GEMMs ----------
    __hip_bfloat16* cQ   = ws;                 // 8192x512
    __hip_bfloat16* cKV  = ws + 4194304;       // 8192x512
    __hip_bfloat16* attn = ws;                 // 8192x1024 (overlays dead cQ+cKV)
    __hip_bfloat16* qC   = ws + 8388608;       // (B,S,H,64)
    __hip_bfloat16* qR   = ws + 16777216;      // (B,S,H,32)
    __hip_bfloat16* kC   = ws + 20971520;      // (B,S,H,64)
    __hip_bfloat16* vT   = ws + 29360128;      // (B,1024,2048)
    __hip_bfloat16* kR   = ws + 37748736;      // (B,S,32)

    gemm_bt<<<dim3(8, 128), blk, 0, stream>>>(x,   W_DQ,  cQ,  8192, 512, 1024, 0, 1, 1, 0);
    gemm_bt<<<dim3(8, 128), blk, 0, stream>>>(x,   W_DKV, cKV, 8192, 512, 1024, 0, 1, 1, 0);
    gemm_bt<<<dim3(1, 128), blk, 0, stream>>>(x,   W_KR,  kR,  8192, 32, 1024, 0, 1, 1, 0);
    gemm_bt<<<dim3(16, 128), blk, 0, stream>>>(cQ,  W_UQ,  qC,  8192, 1024, 512, 0, 0, 1, 0);
    gemm_bt<<<dim3(8, 128), blk, 0, stream>>>(cQ,  W_QR,  qR,  8192, 512, 512, 0, 0, 1, 0);
    gemm_bt<<<dim3(16, 128), blk, 0, stream>>>(cKV, W_UK,  kC,  8192, 1024, 512, 0, 0, 1, 0);
    gemm_bt<<<dim3(16, 128), blk, 0, stream>>>(cKV, W_UV,  vT,  8192, 1024, 512, 1, 0, 1, 0);
    rope_kernel<<<dim3(8192), blk, 0, stream>>>(qR, 2097152, 256);
    rope_kernel<<<dim3(512), blk, 0, stream>>>(kR, 131072, 16);
    // Fused over batches; KVBLK=64: ~31.5KB LDS -> 5 blocks/CU, 20 MFMA per
    // barrier pair per wave, half the barriers/reductions of KVBLK=32.
    mla_attn<<<dim3(32, 16, 4), blk, 0, stream>>>(qC, qR, kC, kR, vT, attn);
    gemm_bt<<<dim3(16, 128), blk, 0, stream>>>(attn, W_O, out, 8192, 1024, 1024, 2, 0, 1, 0);
  } else {
    // ---------- small path: per-batch arena (14.1 MB ws + d_out slice scratch) ----------
    __hip_bfloat16* qc = ws;                   // 2M el
    __hip_bfloat16* qr = ws + 2097152;         // 1M el
    __hip_bfloat16* kc = ws + 3145728;         // 2M el
    __hip_bfloat16* kr = ws + 5242880;         // 64K el
    __hip_bfloat16* F  = ws + 5308416;         // 2M el: cQ_b / cKV_b / attn_b

    for (int b = 0; b < 4; b++) {
      unsigned long long xoff = (unsigned long long)b * 2048 * 1024;
      float* outb = out + (size_t)b * 2097152;              // fp32 slice b
      __hip_bfloat16* vtb = (__hip_bfloat16*)outb;          // scratch inside the slice (dead before final)

      gemm_bt<<<dim3(8, 32), blk, 0, stream>>>(x, W_DQ,  F,  2048, 512, 1024, 0, 1, 1, xoff);
      gemm_bt<<<dim3(16, 32), blk, 0, stream>>>(F, W_UQ,  qc, 2048, 1024, 512, 0, 0, 1, 0);
      gemm_bt<<<dim3(8, 32), blk, 0, stream>>>(F, W_QR,  qr, 2048, 512, 512, 0, 0, 1, 0);
      gemm_bt<<<dim3(8, 32), blk, 0, stream>>>(x, W_DKV, F,  2048, 512, 1024, 0, 1, 1, xoff);
      gemm_bt<<<dim3(16, 32), blk, 0, stream>>>(F, W_UK,  kc, 2048, 1024, 512, 0, 0, 1, 0);
      gemm_bt<<<dim3(16, 32), blk, 0, stream>>>(F, W_UV,  vtb, 2048, 1024, 512, 1, 0, 1, 0);
      gemm_bt<<<dim3(1, 32), blk, 0, stream>>>(x, W_KR,  kr, 2048, 32, 1024, 0, 1, 1, xoff);
      rope_kernel<<<dim3(2048), blk, 0, stream>>>(qr, 524288, 256);
      rope_kernel<<<dim3(128), blk, 0, stream>>>(kr, 32768, 16);
      mla_attn<<<dim3(32, 16, 1), blk, 0, stream>>>(qc, qr, kc, kr, vtb, F);
      gemm_bt<<<dim3(16, 32), blk, 0, stream>>>(F, W_O, outb, 2048, 1024, 1024, 2, 0, 1, 0);
    }
  }
}

// Round 3
// 524.707 us; speedup vs baseline: 1.7308x; 1.1992x over previous
//
#include <hip/hip_runtime.h>
#include <hip/hip_bf16.h>

typedef short short8 __attribute__((ext_vector_type(8)));
typedef float floatx4 __attribute__((ext_vector_type(4)));

__device__ __forceinline__ short f2bf(float x) {
  __hip_bfloat16 h = __float2bfloat16(x);
  return __builtin_bit_cast(short, h);
}

__device__ __forceinline__ short8 load8(const void* __restrict__ p, size_t idx, int f32) {
  if (f32) {
    const float* f = (const float*)p + idx;
    short8 r;
#pragma unroll
    for (int i = 0; i < 8; i++) r[i] = f2bf(f[i]);
    return r;
  }
  return *(const short8*)((const short*)p + idx);
}

// ---------- legacy 64x64 GEMM (small path + tiny N=32 GEMM) ----------
__global__ __launch_bounds__(256) void gemm_bt(
    const void* __restrict__ A,
    const void* __restrict__ Bm,
    void* __restrict__ C,
    int M, int N, int K, int omode,
    int af32, int bf32, unsigned long long aoff)
{
  __shared__ short As[64][72];
  __shared__ short Bs[64][72];
  const int tid  = threadIdx.x;
  const int wave = tid >> 6, lane = tid & 63;
  const int quad = lane >> 4, l15 = lane & 15;
  const int m0 = blockIdx.y * 64, n0 = blockIdx.x * 64;
  const int wr = (wave >> 1) * 32, wc = (wave & 1) * 32;

  floatx4 acc00 = {}, acc01 = {}, acc10 = {}, acc11 = {};

  const int r0 = tid >> 3, kc0 = (tid & 7) << 3;
  const int r1 = r0 + 32;

  for (int k0 = 0; k0 < K; k0 += 64) {
    __syncthreads();
    *(short8*)&As[r0][kc0] = load8(A, aoff + (size_t)(m0 + r0) * K + k0 + kc0, af32);
    *(short8*)&As[r1][kc0] = load8(A, aoff + (size_t)(m0 + r1) * K + k0 + kc0, af32);
    short8 bz = {};
    *(short8*)&Bs[r0][kc0] = (n0 + r0 < N) ? load8(Bm, (size_t)(n0 + r0) * K + k0 + kc0, bf32) : bz;
    *(short8*)&Bs[r1][kc0] = (n0 + r1 < N) ? load8(Bm, (size_t)(n0 + r1) * K + k0 + kc0, bf32) : bz;
    __syncthreads();
#pragma unroll
    for (int kk = 0; kk < 64; kk += 32) {
      short8 a0 = *(const short8*)&As[wr + l15][kk + quad * 8];
      short8 a1 = *(const short8*)&As[wr + 16 + l15][kk + quad * 8];
      short8 b0 = *(const short8*)&Bs[wc + l15][kk + quad * 8];
      short8 b1 = *(const short8*)&Bs[wc + 16 + l15][kk + quad * 8];
      acc00 = __builtin_amdgcn_mfma_f32_16x16x32_bf16(a0, b0, acc00, 0, 0, 0);
      acc01 = __builtin_amdgcn_mfma_f32_16x16x32_bf16(a0, b1, acc01, 0, 0, 0);
      acc10 = __builtin_amdgcn_mfma_f32_16x16x32_bf16(a1, b0, acc10, 0, 0, 0);
      acc11 = __builtin_amdgcn_mfma_f32_16x16x32_bf16(a1, b1, acc11, 0, 0, 0);
    }
  }

  floatx4 accs[2][2] = {{acc00, acc01}, {acc10, acc11}};
#pragma unroll
  for (int i = 0; i < 2; i++)
#pragma unroll
    for (int j = 0; j < 2; j++)
#pragma unroll
      for (int r = 0; r < 4; r++) {
        int row = m0 + wr + i * 16 + quad * 4 + r;
        int col = n0 + wc + j * 16 + l15;
        if (col < N) {
          float v = accs[i][j][r];
          if (omode == 2) {
            ((float*)C)[(size_t)row * N + col] = v;
          } else if (omode == 1) {
            ((__hip_bfloat16*)C)[(((size_t)(row >> 11) * 1024 + col) << 11) + (row & 2047)] =
                __float2bfloat16(v);
          } else {
            ((__hip_bfloat16*)C)[(size_t)row * N + col] = __float2bfloat16(v);
          }
        }
      }
}

// ---------- 128x128 bf16 GEMM: global_load_lds + XOR-swizzled LDS ----------
// A: MxK bf16 row-major. Bm: NxK bf16 row-major (B^T). M%128==0, N%128==0, K%64==0.
// LDS tile [128 rows][8 slots of 8 bf16]; physical slot s of row r holds
// logical slot s^(r&7) (involution; staged by pre-swizzling the global source,
// read back with the same XOR -> conflict-free ds_read_b128).
__global__ __launch_bounds__(256) void gemm128(
    const short* __restrict__ A,
    const short* __restrict__ Bm,
    void* __restrict__ C,
    int M, int N, int K, int omode)
{
  __shared__ short As[128 * 64];
  __shared__ short Bs[128 * 64];
  const int tid  = threadIdx.x;
  const int wave = tid >> 6, lane = tid & 63;
  const int quad = lane >> 4, l15 = lane & 15;
  const int m0 = blockIdx.y * 128, n0 = blockIdx.x * 128;
  const int wr = (wave >> 1) * 64, wc = (wave & 1) * 64;

  floatx4 acc[4][4] = {};

  typedef __attribute__((address_space(3))) short lds_short;
  typedef __attribute__((address_space(1))) const void gbl_void;
  lds_short* Asl = (lds_short*)As;
  lds_short* Bsl = (lds_short*)Bs;

  for (int k0 = 0; k0 < K; k0 += 64) {
    __syncthreads();
    // stage: 1024 chunks of 16B per tile; chunk c -> row=c>>3, slot=c&7.
    // source column pre-swizzled so linear LDS + swizzled read is correct.
#pragma unroll
    for (int it = 0; it < 4; it++) {
      int c = it * 256 + tid;
      int row = c >> 3, s = c & 7;
      int gcol = ((s ^ (row & 7)) << 3);
      const short* ga = &A[(size_t)(m0 + row) * K + k0 + gcol];
      const short* gb = &Bm[(size_t)(n0 + row) * K + k0 + gcol];
      __builtin_amdgcn_global_load_lds((gbl_void*)ga,
          (__attribute__((address_space(3))) void*)(Asl + (size_t)c * 8), 16, 0, 0);
      __builtin_amdgcn_global_load_lds((gbl_void*)gb,
          (__attribute__((address_space(3))) void*)(Bsl + (size_t)c * 8), 16, 0, 0);
    }
    __syncthreads();
#pragma unroll
    for (int kk = 0; kk < 64; kk += 32) {
      const int qb = (kk >> 3) + quad;     // logical 16B-slot 0..7
      short8 af[4], bf[4];
#pragma unroll
      for (int i = 0; i < 4; i++) {
        int ar = wr + i * 16 + l15;
        af[i] = *(const short8*)&As[ar * 64 + ((qb ^ (ar & 7)) << 3)];
        int br = wc + i * 16 + l15;
        bf[i] = *(const short8*)&Bs[br * 64 + ((qb ^ (br & 7)) << 3)];
      }
      __builtin_amdgcn_s_setprio(1);
#pragma unroll
      for (int i = 0; i < 4; i++)
#pragma unroll
        for (int j = 0; j < 4; j++)
          acc[i][j] = __builtin_amdgcn_mfma_f32_16x16x32_bf16(af[i], bf[j], acc[i][j], 0, 0, 0);
      __builtin_amdgcn_s_setprio(0);
    }
  }

#pragma unroll
  for (int i = 0; i < 4; i++)
#pragma unroll
    for (int j = 0; j < 4; j++)
#pragma unroll
      for (int r = 0; r < 4; r++) {
        int row = m0 + wr + i * 16 + quad * 4 + r;
        int col = n0 + wc + j * 16 + l15;
        float v = acc[i][j][r];
        if (omode == 2) {
          ((float*)C)[(size_t)row * N + col] = v;
        } else if (omode == 1) {
          ((__hip_bfloat16*)C)[(((size_t)(row >> 11) * 1024 + col) << 11) + (row & 2047)] =
              __float2bfloat16(v);
        } else {
          ((__hip_bfloat16*)C)[(size_t)row * N + col] = __float2bfloat16(v);
        }
      }
}

// ---------- f32 -> bf16 converters ----------
__device__ __forceinline__ void cvt_chunk(const float* __restrict__ s, short* __restrict__ d) {
  float4 u = ((const float4*)s)[0];
  float4 v = ((const float4*)s)[1];
  short8 o;
  o[0] = f2bf(u.x); o[1] = f2bf(u.y); o[2] = f2bf(u.z); o[3] = f2bf(u.w);
  o[4] = f2bf(v.x); o[5] = f2bf(v.y); o[6] = f2bf(v.z); o[7] = f2bf(v.w);
  *(short8*)d = o;
}

// x + 6 weights, packed contiguously into dst (chunk = 8 elements).
__global__ __launch_bounds__(256) void cvt_all(
    const float* __restrict__ x,    const float* __restrict__ wdq,
    const float* __restrict__ wdkv, const float* __restrict__ wuq,
    const float* __restrict__ wqr,  const float* __restrict__ wuk,
    const float* __restrict__ wuv,  short* __restrict__ dst)
{
  int g = blockIdx.x * 256 + threadIdx.x;
  const float* src; int loc;
  if      (g < 1048576) { src = x;    loc = g; }
  else if (g < 1114112) { src = wdq;  loc = g - 1048576; }
  else if (g < 1179648) { src = wdkv; loc = g - 1114112; }
  else if (g < 1245184) { src = wuq;  loc = g - 1179648; }
  else if (g < 1277952) { src = wqr;  loc = g - 1245184; }
  else if (g < 1343488) { src = wuk;  loc = g - 1277952; }
  else                  { src = wuv;  loc = g - 1343488; }
  cvt_chunk(src + (size_t)loc * 8, dst + (size_t)g * 8);
}

__global__ __launch_bounds__(256) void cvt_f32_bf16(
    const float* __restrict__ src, short* __restrict__ dst, int nchunk)
{
  int g = blockIdx.x * 256 + threadIdx.x;
  if (g >= nchunk) return;
  cvt_chunk(src + (size_t)g * 8, dst + (size_t)g * 8);
}

// In-place interleaved RoPE on internal bf16 buffers.
__global__ __launch_bounds__(256) void rope_kernel(__hip_bfloat16* p, int n_pairs, int ppp) {
  int g = blockIdx.x * 256 + threadIdx.x;
  if (g >= n_pairs) return;
  int i = g & 15;
  int pos = (g / ppp) & 2047;
  float inv_freq = powf(10000.0f, -(float)i * (1.0f / 16.0f));
  float ang = (float)pos * inv_freq;
  float sn, cs;
  sincosf(ang, &sn, &cs);
  float x1 = __bfloat162float(p[2 * g]);
  float x2 = __bfloat162float(p[2 * g + 1]);
  p[2 * g]     = __float2bfloat16(x1 * cs - x2 * sn);
  p[2 * g + 1] = __float2bfloat16(x1 * sn + x2 * cs);
}

// Batched causal flash attention, KVBLK=64.
__global__ __launch_bounds__(256) void mla_attn(
    const __hip_bfloat16* __restrict__ qC,
    const __hip_bfloat16* __restrict__ qR,
    const __hip_bfloat16* __restrict__ kC,
    const __hip_bfloat16* __restrict__ kR,
    const __hip_bfloat16* __restrict__ vT,
    __hip_bfloat16* __restrict__ O)
{
  const int tid  = threadIdx.x;
  const int wave = tid >> 6, lane = tid & 63;
  const int quad = lane >> 4, l15 = lane & 15;
  const int h = blockIdx.y;
  const int q0 = (gridDim.x - 1 - blockIdx.x) * 64;
  const int b = blockIdx.z;

  __shared__ short Ks[64][104];
  __shared__ short Vt[64][72];
  __shared__ short Ps[4][16][76];

  const short* qCs = reinterpret_cast<const short*>(qC) + (size_t)b * 2097152;
  const short* qRs = reinterpret_cast<const short*>(qR) + (size_t)b * 1048576;
  const short* kCs = reinterpret_cast<const short*>(kC) + (size_t)b * 2097152;
  const short* kRs = reinterpret_cast<const short*>(kR) + (size_t)b * 65536;
  const short* Vs  = reinterpret_cast<const short*>(vT) + (size_t)b * 2097152;
  __hip_bfloat16* Ob = O + (size_t)b * 2097152;

  const int qrow = q0 + wave * 16 + l15;
  const size_t qcbase = ((size_t)qrow * 16 + h) * 64;
  const size_t qrbase = ((size_t)qrow * 16 + h) * 32;
  short8 aq0 = *(const short8*)&qCs[qcbase + quad * 8];
  short8 aq1 = *(const short8*)&qCs[qcbase + 32 + quad * 8];
  short8 aq2 = *(const short8*)&qRs[qrbase + quad * 8];

  const float MASKV = -30000.0f;
  float mrow[4], lrow[4];
  floatx4 accO[4] = {};
#pragma unroll
  for (int r = 0; r < 4; r++) { mrow[r] = MASKV; lrow[r] = 0.f; }

  const float scale = 0.10206207261596575f;  // 1/sqrt(96)

  const int nkt = (q0 >> 6) + 1;
  for (int kt = 0; kt < nkt; kt++) {
    const int k0 = kt * 64;
    __syncthreads();
    {
#pragma unroll
      for (int it = 0; it < 3; it++) {
        int c = tid + it * 256;
        int key = c / 12, seg = c - key * 12;
        short8 kv;
        if (seg < 8) kv = *(const short8*)&kCs[((size_t)(k0 + key) * 16 + h) * 64 + seg * 8];
        else         kv = *(const short8*)&kRs[(size_t)(k0 + key) * 32 + (seg - 8) * 8];
        *(short8*)&Ks[key][seg * 8] = kv;
      }
    }
    {
#pragma unroll
      for (int it = 0; it < 2; it++) {
        int c = tid + it * 256;
        int dv = c >> 3, kc = (c & 7) << 3;
        short8 vv = *(const short8*)&Vs[((size_t)(h * 64 + dv)) * 2048 + k0 + kc];
        *(short8*)&Vt[dv][kc] = vv;
      }
    }
    __syncthreads();

    float st[4][4];
    __builtin_amdgcn_s_setprio(1);
#pragma unroll
    for (int j = 0; j < 4; j++) {
      short8 b0 = *(const short8*)&Ks[j * 16 + l15][quad * 8];
      short8 b1 = *(const short8*)&Ks[j * 16 + l15][32 + quad * 8];
      short8 b2 = *(const short8*)&Ks[j * 16 + l15][64 + quad * 8];
      floatx4 s = {};
      s = __builtin_amdgcn_mfma_f32_16x16x32_bf16(aq0, b0, s, 0, 0, 0);
      s = __builtin_amdgcn_mfma_f32_16x16x32_bf16(aq1, b1, s, 0, 0, 0);
      s = __builtin_amdgcn_mfma_f32_16x16x32_bf16(aq2, b2, s, 0, 0, 0);
      const int kpos = k0 + j * 16 + l15;
#pragma unroll
      for (int r = 0; r < 4; r++) {
        const int qpos = q0 + wave * 16 + quad * 4 + r;
        float t = fminf(fmaxf(s[r], -80.f), 80.f) * scale;
        st[j][r] = (kpos <= qpos) ? t : MASKV;
      }
    }
    __builtin_amdgcn_s_setprio(0);

    float ps[4][4], alpha[4];
#pragma unroll
    for (int r = 0; r < 4; r++) {
      float tm = fmaxf(fmaxf(st[0][r], st[1][r]), fmaxf(st[2][r], st[3][r]));
      tm = fmaxf(tm, __shfl_xor(tm, 1));
      tm = fmaxf(tm, __shfl_xor(tm, 2));
      tm = fmaxf(tm, __shfl_xor(tm, 4));
      tm = fmaxf(tm, __shfl_xor(tm, 8));
      float mnew = fmaxf(mrow[r], tm);
      alpha[r] = __expf(mrow[r] - mnew);
      mrow[r] = mnew;
      float rs = 0.f;
#pragma unroll
      for (int j = 0; j < 4; j++) {
        float p = __expf(st[j][r] - mnew);
        ps[j][r] = p;
        rs += p;
      }
      lrow[r] = lrow[r] * alpha[r] + rs;
    }
#pragma unroll
    for (int c = 0; c < 4; c++)
#pragma unroll
      for (int r = 0; r < 4; r++) accO[c][r] *= alpha[r];

#pragma unroll
    for (int j = 0; j < 4; j++)
#pragma unroll
      for (int r = 0; r < 4; r++)
        Ps[wave][quad * 4 + r][j * 16 + l15] = f2bf(ps[j][r]);
    short8 ap0 = *(const short8*)&Ps[wave][l15][quad * 8];
    short8 ap1 = *(const short8*)&Ps[wave][l15][32 + quad * 8];
    __builtin_amdgcn_s_setprio(1);
#pragma unroll
    for (int c = 0; c < 4; c++) {
      short8 bv0 = *(const short8*)&Vt[c * 16 + l15][quad * 8];
      short8 bv1 = *(const short8*)&Vt[c * 16 + l15][32 + quad * 8];
      accO[c] = __builtin_amdgcn_mfma_f32_16x16x32_bf16(ap0, bv0, accO[c], 0, 0, 0);
      accO[c] = __builtin_amdgcn_mfma_f32_16x16x32_bf16(ap1, bv1, accO[c], 0, 0, 0);
    }
    __builtin_amdgcn_s_setprio(0);
  }

#pragma unroll
  for (int r = 0; r < 4; r++) {
    float rs = lrow[r];
    rs += __shfl_xor(rs, 1);
    rs += __shfl_xor(rs, 2);
    rs += __shfl_xor(rs, 4);
    rs += __shfl_xor(rs, 8);
    float inv = (rs > 0.f) ? 1.f / rs : 0.f;
    int s = q0 + wave * 16 + quad * 4 + r;
    size_t obase = (size_t)s * 1024 + h * 64;
#pragma unroll
    for (int c = 0; c < 4; c++)
      Ob[obase + c * 16 + l15] = __float2bfloat16(accO[c][r] * inv);
  }
}

extern "C" void kernel_launch(void* const* d_in, const int* in_sizes, int n_in,
                              void* d_out, int out_size, void* d_ws, size_t ws_size,
                              hipStream_t stream) {
  const void* x     = d_in[0];
  const void* W_DQ  = d_in[1];
  const void* W_UQ  = d_in[2];
  const void* W_QR  = d_in[3];
  const void* W_DKV = d_in[4];
  const void* W_UK  = d_in[5];
  const void* W_UV  = d_in[6];
  const void* W_KR  = d_in[7];
  const void* W_O   = d_in[8];
  float* out = (float*)d_out;
  __hip_bfloat16* ws = (__hip_bfloat16*)d_ws;

  dim3 blk(256);

  if (ws_size >= (size_t)76021760) {
    // ---------- big path ----------
    __hip_bfloat16* cQ   = ws;                 // 8192x512
    __hip_bfloat16* cKV  = ws + 4194304;       // 8192x512
    __hip_bfloat16* attn = ws;                 // 8192x1024 (overlays dead cQ+cKV)
    __hip_bfloat16* qC   = ws + 8388608;       // (B,S,H,64)
    __hip_bfloat16* qR   = ws + 16777216;      // (B,S,H,32)
    __hip_bfloat16* kC   = ws + 20971520;      // (B,S,H,64)
    __hip_bfloat16* vT   = ws + 29360128;      // (B,1024,2048)
    __hip_bfloat16* kR   = ws + 37748736;      // (B,S,32)

    // bf16 scratch inside d_out (dead until final GEMM overwrites it):
    short* xb   = (short*)out;                 // 8,388,608 el (x as bf16)
    short* wb   = xb + 8388608;                // packed weights
    short* wDQ  = wb;                          // 524288
    short* wDKV = wb + 524288;                 // 524288
    short* wUQ  = wb + 1048576;                // 524288
    short* wQR  = wb + 1572864;                // 262144
    short* wUK  = wb + 1835008;                // 524288
    short* wUV  = wb + 2359296;                // 524288
    short* wO   = (short*)qC;                  // W_O bf16, written AFTER attn (qC dead)

    cvt_all<<<dim3(5504), blk, 0, stream>>>((const float*)x, (const float*)W_DQ,
        (const float*)W_DKV, (const float*)W_UQ, (const float*)W_QR,
        (const float*)W_UK, (const float*)W_UV, xb);

    gemm128<<<dim3(4, 64), blk, 0, stream>>>(xb, wDQ,  cQ,  8192, 512, 1024, 0);
    gemm128<<<dim3(4, 64), blk, 0, stream>>>(xb, wDKV, cKV, 8192, 512, 1024, 0);
    gemm_bt<<<dim3(1, 128), blk, 0, stream>>>(xb, W_KR, kR, 8192, 32, 1024, 0, 0, 1, 0);
    gemm128<<<dim3(8, 64), blk, 0, stream>>>((short*)cQ,  wUQ, qC, 8192, 1024, 512, 0);
    gemm128<<<dim3(4, 64), blk, 0, stream>>>((short*)cQ,  wQR, qR, 8192, 512, 512, 0);
    gemm128<<<dim3(8, 64), blk, 0, stream>>>((short*)cKV, wUK, kC, 8192, 1024, 512, 0);
    gemm128<<<dim3(8, 64), blk, 0, stream>>>((short*)cKV, wUV, vT, 8192, 1024, 512, 1);
    rope_kernel<<<dim3(8192), blk, 0, stream>>>(qR, 2097152, 256);
    rope_kernel<<<dim3(512), blk, 0, stream>>>(kR, 131072, 16);
    mla_attn<<<dim3(32, 16, 4), blk, 0, stream>>>(qC, qR, kC, kR, vT, attn);
    cvt_f32_bf16<<<dim3(512), blk, 0, stream>>>((const float*)W_O, wO, 131072);
    gemm128<<<dim3(8, 64), blk, 0, stream>>>((short*)attn, wO, out, 8192, 1024, 1024, 2);
  } else {
    // ---------- small path: per-batch arena (unchanged fallback) ----------
    __hip_bfloat16* qc = ws;
    __hip_bfloat16* qr = ws + 2097152;
    __hip_bfloat16* kc = ws + 3145728;
    __hip_bfloat16* kr = ws + 5242880;
    __hip_bfloat16* F  = ws + 5308416;

    for (int b = 0; b < 4; b++) {
      unsigned long long xoff = (unsigned long long)b * 2048 * 1024;
      float* outb = out + (size_t)b * 2097152;
      __hip_bfloat16* vtb = (__hip_bfloat16*)outb;

      gemm_bt<<<dim3(8, 32), blk, 0, stream>>>(x, W_DQ,  F,  2048, 512, 1024, 0, 1, 1, xoff);
      gemm_bt<<<dim3(16, 32), blk, 0, stream>>>(F, W_UQ,  qc, 2048, 1024, 512, 0, 0, 1, 0);
      gemm_bt<<<dim3(8, 32), blk, 0, stream>>>(F, W_QR,  qr, 2048, 512, 512, 0, 0, 1, 0);
      gemm_bt<<<dim3(8, 32), blk, 0, stream>>>(x, W_DKV, F,  2048, 512, 1024, 0, 1, 1, xoff);
      gemm_bt<<<dim3(16, 32), blk, 0, stream>>>(F, W_UK,  kc, 2048, 1024, 512, 0, 0, 1, 0);
      gemm_bt<<<dim3(16, 32), blk, 0, stream>>>(F, W_UV,  vtb, 2048, 1024, 512, 1, 0, 1, 0);
      gemm_bt<<<dim3(1, 32), blk, 0, stream>>>(x, W_KR,  kr, 2048, 32, 1024, 0, 1, 1, xoff);
      rope_kernel<<<dim3(2048), blk, 0, stream>>>(qr, 524288, 256);
      rope_kernel<<<dim3(128), blk, 0, stream>>>(kr, 32768, 16);
      mla_attn<<<dim3(32, 16, 1), blk, 0, stream>>>(qc, qr, kc, kr, vtb, F);
      gemm_bt<<<dim3(16, 32), blk, 0, stream>>>(F, W_O, outb, 2048, 1024, 1024, 2, 0, 1, 0);
    }
  }
}

// Round 4
// 470.611 us; speedup vs baseline: 1.9297x; 1.1149x over previous
//
#include <hip/hip_runtime.h>
#include <hip/hip_bf16.h>

typedef short short8 __attribute__((ext_vector_type(8)));
typedef float floatx4 __attribute__((ext_vector_type(4)));

__device__ __forceinline__ short f2bf(float x) {
  __hip_bfloat16 h = __float2bfloat16(x);
  return __builtin_bit_cast(short, h);
}

__device__ __forceinline__ short8 load8(const void* __restrict__ p, size_t idx, int f32) {
  if (f32) {
    const float* f = (const float*)p + idx;
    short8 r;
#pragma unroll
    for (int i = 0; i < 8; i++) r[i] = f2bf(f[i]);
    return r;
  }
  return *(const short8*)((const short*)p + idx);
}

// ---------- legacy 64x64 GEMM (small path + tiny N=32 GEMM) ----------
__global__ __launch_bounds__(256) void gemm_bt(
    const void* __restrict__ A,
    const void* __restrict__ Bm,
    void* __restrict__ C,
    int M, int N, int K, int omode,
    int af32, int bf32, unsigned long long aoff)
{
  __shared__ short As[64][72];
  __shared__ short Bs[64][72];
  const int tid  = threadIdx.x;
  const int wave = tid >> 6, lane = tid & 63;
  const int quad = lane >> 4, l15 = lane & 15;
  const int m0 = blockIdx.y * 64, n0 = blockIdx.x * 64;
  const int wr = (wave >> 1) * 32, wc = (wave & 1) * 32;

  floatx4 acc00 = {}, acc01 = {}, acc10 = {}, acc11 = {};

  const int r0 = tid >> 3, kc0 = (tid & 7) << 3;
  const int r1 = r0 + 32;

  for (int k0 = 0; k0 < K; k0 += 64) {
    __syncthreads();
    *(short8*)&As[r0][kc0] = load8(A, aoff + (size_t)(m0 + r0) * K + k0 + kc0, af32);
    *(short8*)&As[r1][kc0] = load8(A, aoff + (size_t)(m0 + r1) * K + k0 + kc0, af32);
    short8 bz = {};
    *(short8*)&Bs[r0][kc0] = (n0 + r0 < N) ? load8(Bm, (size_t)(n0 + r0) * K + k0 + kc0, bf32) : bz;
    *(short8*)&Bs[r1][kc0] = (n0 + r1 < N) ? load8(Bm, (size_t)(n0 + r1) * K + k0 + kc0, bf32) : bz;
    __syncthreads();
#pragma unroll
    for (int kk = 0; kk < 64; kk += 32) {
      short8 a0 = *(const short8*)&As[wr + l15][kk + quad * 8];
      short8 a1 = *(const short8*)&As[wr + 16 + l15][kk + quad * 8];
      short8 b0 = *(const short8*)&Bs[wc + l15][kk + quad * 8];
      short8 b1 = *(const short8*)&Bs[wc + 16 + l15][kk + quad * 8];
      acc00 = __builtin_amdgcn_mfma_f32_16x16x32_bf16(a0, b0, acc00, 0, 0, 0);
      acc01 = __builtin_amdgcn_mfma_f32_16x16x32_bf16(a0, b1, acc01, 0, 0, 0);
      acc10 = __builtin_amdgcn_mfma_f32_16x16x32_bf16(a1, b0, acc10, 0, 0, 0);
      acc11 = __builtin_amdgcn_mfma_f32_16x16x32_bf16(a1, b1, acc11, 0, 0, 0);
    }
  }

  floatx4 accs[2][2] = {{acc00, acc01}, {acc10, acc11}};
#pragma unroll
  for (int i = 0; i < 2; i++)
#pragma unroll
    for (int j = 0; j < 2; j++)
#pragma unroll
      for (int r = 0; r < 4; r++) {
        int row = m0 + wr + i * 16 + quad * 4 + r;
        int col = n0 + wc + j * 16 + l15;
        if (col < N) {
          float v = accs[i][j][r];
          if (omode == 2) {
            ((float*)C)[(size_t)row * N + col] = v;
          } else if (omode == 1) {
            ((__hip_bfloat16*)C)[(((size_t)(row >> 11) * 1024 + col) << 11) + (row & 2047)] =
                __float2bfloat16(v);
          } else {
            ((__hip_bfloat16*)C)[(size_t)row * N + col] = __float2bfloat16(v);
          }
        }
      }
}

// ---------- 128x128 bf16 GEMM: global_load_lds + XOR-swizzled LDS ----------
__global__ __launch_bounds__(256) void gemm128(
    const short* __restrict__ A,
    const short* __restrict__ Bm,
    void* __restrict__ C,
    int M, int N, int K, int omode)
{
  __shared__ short As[128 * 64];
  __shared__ short Bs[128 * 64];
  const int tid  = threadIdx.x;
  const int wave = tid >> 6, lane = tid & 63;
  const int quad = lane >> 4, l15 = lane & 15;
  const int m0 = blockIdx.y * 128, n0 = blockIdx.x * 128;
  const int wr = (wave >> 1) * 64, wc = (wave & 1) * 64;

  floatx4 acc[4][4] = {};

  typedef __attribute__((address_space(3))) short lds_short;
  typedef __attribute__((address_space(1))) const void gbl_void;
  lds_short* Asl = (lds_short*)As;
  lds_short* Bsl = (lds_short*)Bs;

  for (int k0 = 0; k0 < K; k0 += 64) {
    __syncthreads();
#pragma unroll
    for (int it = 0; it < 4; it++) {
      int c = it * 256 + tid;
      int row = c >> 3, s = c & 7;
      int gcol = ((s ^ (row & 7)) << 3);
      const short* ga = &A[(size_t)(m0 + row) * K + k0 + gcol];
      const short* gb = &Bm[(size_t)(n0 + row) * K + k0 + gcol];
      __builtin_amdgcn_global_load_lds((gbl_void*)ga,
          (__attribute__((address_space(3))) void*)(Asl + (size_t)c * 8), 16, 0, 0);
      __builtin_amdgcn_global_load_lds((gbl_void*)gb,
          (__attribute__((address_space(3))) void*)(Bsl + (size_t)c * 8), 16, 0, 0);
    }
    __syncthreads();
#pragma unroll
    for (int kk = 0; kk < 64; kk += 32) {
      const int qb = (kk >> 3) + quad;
      short8 af[4], bf[4];
#pragma unroll
      for (int i = 0; i < 4; i++) {
        int ar = wr + i * 16 + l15;
        af[i] = *(const short8*)&As[ar * 64 + ((qb ^ (ar & 7)) << 3)];
        int br = wc + i * 16 + l15;
        bf[i] = *(const short8*)&Bs[br * 64 + ((qb ^ (br & 7)) << 3)];
      }
      __builtin_amdgcn_s_setprio(1);
#pragma unroll
      for (int i = 0; i < 4; i++)
#pragma unroll
        for (int j = 0; j < 4; j++)
          acc[i][j] = __builtin_amdgcn_mfma_f32_16x16x32_bf16(af[i], bf[j], acc[i][j], 0, 0, 0);
      __builtin_amdgcn_s_setprio(0);
    }
  }

#pragma unroll
  for (int i = 0; i < 4; i++)
#pragma unroll
    for (int j = 0; j < 4; j++)
#pragma unroll
      for (int r = 0; r < 4; r++) {
        int row = m0 + wr + i * 16 + quad * 4 + r;
        int col = n0 + wc + j * 16 + l15;
        float v = acc[i][j][r];
        if (omode == 2) {
          ((float*)C)[(size_t)row * N + col] = v;
        } else if (omode == 1) {
          ((__hip_bfloat16*)C)[(((size_t)(row >> 11) * 1024 + col) << 11) + (row & 2047)] =
              __float2bfloat16(v);
        } else {
          ((__hip_bfloat16*)C)[(size_t)row * N + col] = __float2bfloat16(v);
        }
      }
}

// ---------- f32 -> bf16 converters ----------
__device__ __forceinline__ void cvt_chunk(const float* __restrict__ s, short* __restrict__ d) {
  float4 u = ((const float4*)s)[0];
  float4 v = ((const float4*)s)[1];
  short8 o;
  o[0] = f2bf(u.x); o[1] = f2bf(u.y); o[2] = f2bf(u.z); o[3] = f2bf(u.w);
  o[4] = f2bf(v.x); o[5] = f2bf(v.y); o[6] = f2bf(v.z); o[7] = f2bf(v.w);
  *(short8*)d = o;
}

__global__ __launch_bounds__(256) void cvt_all(
    const float* __restrict__ x,    const float* __restrict__ wdq,
    const float* __restrict__ wdkv, const float* __restrict__ wuq,
    const float* __restrict__ wqr,  const float* __restrict__ wuk,
    const float* __restrict__ wuv,  short* __restrict__ dst)
{
  int g = blockIdx.x * 256 + threadIdx.x;
  const float* src; int loc;
  if      (g < 1048576) { src = x;    loc = g; }
  else if (g < 1114112) { src = wdq;  loc = g - 1048576; }
  else if (g < 1179648) { src = wdkv; loc = g - 1114112; }
  else if (g < 1245184) { src = wuq;  loc = g - 1179648; }
  else if (g < 1277952) { src = wqr;  loc = g - 1245184; }
  else if (g < 1343488) { src = wuk;  loc = g - 1277952; }
  else                  { src = wuv;  loc = g - 1343488; }
  cvt_chunk(src + (size_t)loc * 8, dst + (size_t)g * 8);
}

__global__ __launch_bounds__(256) void cvt_f32_bf16(
    const float* __restrict__ src, short* __restrict__ dst, int nchunk)
{
  int g = blockIdx.x * 256 + threadIdx.x;
  if (g >= nchunk) return;
  cvt_chunk(src + (size_t)g * 8, dst + (size_t)g * 8);
}

// In-place interleaved RoPE on internal bf16 buffers.
__global__ __launch_bounds__(256) void rope_kernel(__hip_bfloat16* p, int n_pairs, int ppp) {
  int g = blockIdx.x * 256 + threadIdx.x;
  if (g >= n_pairs) return;
  int i = g & 15;
  int pos = (g / ppp) & 2047;
  float inv_freq = powf(10000.0f, -(float)i * (1.0f / 16.0f));
  float ang = (float)pos * inv_freq;
  float sn, cs;
  sincosf(ang, &sn, &cs);
  float x1 = __bfloat162float(p[2 * g]);
  float x2 = __bfloat162float(p[2 * g + 1]);
  p[2 * g]     = __float2bfloat16(x1 * cs - x2 * sn);
  p[2 * g + 1] = __float2bfloat16(x1 * sn + x2 * cs);
}

// Batched causal flash attention, KVBLK=64, FIXED-MAX softmax.
// Scores are clipped to +-80 then scaled by 1/sqrt(96), so every score is
// <= 80/sqrt(96) = 8.1649658. Using that constant as the softmax max removes
// all online-max state (max shfl-reduce, alpha, accO rescale) exactly.
// p = exp2(clip(s)*SC2 - CL2), SC2 = scale*log2e, CL2 = 8.1649658*log2e.
__global__ __launch_bounds__(256) void mla_attn(
    const __hip_bfloat16* __restrict__ qC,
    const __hip_bfloat16* __restrict__ qR,
    const __hip_bfloat16* __restrict__ kC,
    const __hip_bfloat16* __restrict__ kR,
    const __hip_bfloat16* __restrict__ vT,
    __hip_bfloat16* __restrict__ O)
{
  const int tid  = threadIdx.x;
  const int wave = tid >> 6, lane = tid & 63;
  const int quad = lane >> 4, l15 = lane & 15;
  const int h = blockIdx.y;
  const int q0 = (gridDim.x - 1 - blockIdx.x) * 64;
  const int b = blockIdx.z;

  __shared__ short Ks[64][104];
  __shared__ short Vt[64][72];
  __shared__ short Ps[4][16][76];

  const short* qCs = reinterpret_cast<const short*>(qC) + (size_t)b * 2097152;
  const short* qRs = reinterpret_cast<const short*>(qR) + (size_t)b * 1048576;
  const short* kCs = reinterpret_cast<const short*>(kC) + (size_t)b * 2097152;
  const short* kRs = reinterpret_cast<const short*>(kR) + (size_t)b * 65536;
  const short* Vs  = reinterpret_cast<const short*>(vT) + (size_t)b * 2097152;
  __hip_bfloat16* Ob = O + (size_t)b * 2097152;

  const int qrow = q0 + wave * 16 + l15;
  const size_t qcbase = ((size_t)qrow * 16 + h) * 64;
  const size_t qrbase = ((size_t)qrow * 16 + h) * 32;
  short8 aq0 = *(const short8*)&qCs[qcbase + quad * 8];
  short8 aq1 = *(const short8*)&qCs[qcbase + 32 + quad * 8];
  short8 aq2 = *(const short8*)&qRs[qrbase + quad * 8];

  float lrow[4] = {0.f, 0.f, 0.f, 0.f};   // per-lane partial sums
  floatx4 accO[4] = {};

  const float SC2 = 0.14724445f;   // (1/sqrt(96)) * log2(e)
  const float CL2 = 11.7795557f;   // (80/sqrt(96)) * log2(e)

  const int nkt = (q0 >> 6) + 1;
  for (int kt = 0; kt < nkt; kt++) {
    const int k0 = kt * 64;
    const bool diag = (kt == nkt - 1);   // only diagonal tile needs the causal mask
    __syncthreads();
    {
#pragma unroll
      for (int it = 0; it < 3; it++) {
        int c = tid + it * 256;
        int key = c / 12, seg = c - key * 12;
        short8 kv;
        if (seg < 8) kv = *(const short8*)&kCs[((size_t)(k0 + key) * 16 + h) * 64 + seg * 8];
        else         kv = *(const short8*)&kRs[(size_t)(k0 + key) * 32 + (seg - 8) * 8];
        *(short8*)&Ks[key][seg * 8] = kv;
      }
    }
    {
#pragma unroll
      for (int it = 0; it < 2; it++) {
        int c = tid + it * 256;
        int dv = c >> 3, kc = (c & 7) << 3;
        short8 vv = *(const short8*)&Vs[((size_t)(h * 64 + dv)) * 2048 + k0 + kc];
        *(short8*)&Vt[dv][kc] = vv;
      }
    }
    __syncthreads();

    float ps[4][4];
    __builtin_amdgcn_s_setprio(1);
#pragma unroll
    for (int j = 0; j < 4; j++) {
      short8 b0 = *(const short8*)&Ks[j * 16 + l15][quad * 8];
      short8 b1 = *(const short8*)&Ks[j * 16 + l15][32 + quad * 8];
      short8 b2 = *(const short8*)&Ks[j * 16 + l15][64 + quad * 8];
      floatx4 s = {};
      s = __builtin_amdgcn_mfma_f32_16x16x32_bf16(aq0, b0, s, 0, 0, 0);
      s = __builtin_amdgcn_mfma_f32_16x16x32_bf16(aq1, b1, s, 0, 0, 0);
      s = __builtin_amdgcn_mfma_f32_16x16x32_bf16(aq2, b2, s, 0, 0, 0);
      const int kpos = k0 + j * 16 + l15;
#pragma unroll
      for (int r = 0; r < 4; r++) {
        float t = fminf(fmaxf(s[r], -80.f), 80.f) * SC2 - CL2;  // clip BEFORE scale (ref order)
        if (diag) {
          const int qpos = q0 + wave * 16 + quad * 4 + r;
          if (kpos > qpos) t = -12000.f;   // exp2 -> exactly 0
        }
        float p = exp2f(t);
        ps[j][r] = p;
        lrow[r] += p;
      }
    }
    __builtin_amdgcn_s_setprio(0);

#pragma unroll
    for (int j = 0; j < 4; j++)
#pragma unroll
      for (int r = 0; r < 4; r++)
        Ps[wave][quad * 4 + r][j * 16 + l15] = f2bf(ps[j][r]);
    short8 ap0 = *(const short8*)&Ps[wave][l15][quad * 8];
    short8 ap1 = *(const short8*)&Ps[wave][l15][32 + quad * 8];
    __builtin_amdgcn_s_setprio(1);
#pragma unroll
    for (int c = 0; c < 4; c++) {
      short8 bv0 = *(const short8*)&Vt[c * 16 + l15][quad * 8];
      short8 bv1 = *(const short8*)&Vt[c * 16 + l15][32 + quad * 8];
      accO[c] = __builtin_amdgcn_mfma_f32_16x16x32_bf16(ap0, bv0, accO[c], 0, 0, 0);
      accO[c] = __builtin_amdgcn_mfma_f32_16x16x32_bf16(ap1, bv1, accO[c], 0, 0, 0);
    }
    __builtin_amdgcn_s_setprio(0);
  }

#pragma unroll
  for (int r = 0; r < 4; r++) {
    float rs = lrow[r];
    rs += __shfl_xor(rs, 1);
    rs += __shfl_xor(rs, 2);
    rs += __shfl_xor(rs, 4);
    rs += __shfl_xor(rs, 8);
    float inv = (rs > 0.f) ? 1.f / rs : 0.f;
    int s = q0 + wave * 16 + quad * 4 + r;
    size_t obase = (size_t)s * 1024 + h * 64;
#pragma unroll
    for (int c = 0; c < 4; c++)
      Ob[obase + c * 16 + l15] = __float2bfloat16(accO[c][r] * inv);
  }
}

extern "C" void kernel_launch(void* const* d_in, const int* in_sizes, int n_in,
                              void* d_out, int out_size, void* d_ws, size_t ws_size,
                              hipStream_t stream) {
  const void* x     = d_in[0];
  const void* W_DQ  = d_in[1];
  const void* W_UQ  = d_in[2];
  const void* W_QR  = d_in[3];
  const void* W_DKV = d_in[4];
  const void* W_UK  = d_in[5];
  const void* W_UV  = d_in[6];
  const void* W_KR  = d_in[7];
  const void* W_O   = d_in[8];
  float* out = (float*)d_out;
  __hip_bfloat16* ws = (__hip_bfloat16*)d_ws;

  dim3 blk(256);

  if (ws_size >= (size_t)76021760) {
    // ---------- big path ----------
    __hip_bfloat16* cQ   = ws;                 // 8192x512
    __hip_bfloat16* cKV  = ws + 4194304;       // 8192x512
    __hip_bfloat16* attn = ws;                 // 8192x1024 (overlays dead cQ+cKV)
    __hip_bfloat16* qC   = ws + 8388608;       // (B,S,H,64)
    __hip_bfloat16* qR   = ws + 16777216;      // (B,S,H,32)
    __hip_bfloat16* kC   = ws + 20971520;      // (B,S,H,64)
    __hip_bfloat16* vT   = ws + 29360128;      // (B,1024,2048)
    __hip_bfloat16* kR   = ws + 37748736;      // (B,S,32)

    // bf16 scratch inside d_out (dead until final GEMM overwrites it):
    short* xb   = (short*)out;                 // 8,388,608 el (x as bf16)
    short* wb   = xb + 8388608;                // packed weights
    short* wDQ  = wb;                          // 524288
    short* wDKV = wb + 524288;                 // 524288
    short* wUQ  = wb + 1048576;                // 524288
    short* wQR  = wb + 1572864;                // 262144
    short* wUK  = wb + 1835008;                // 524288
    short* wUV  = wb + 2359296;                // 524288
    short* wO   = (short*)qC;                  // W_O bf16, written AFTER attn (qC dead)

    cvt_all<<<dim3(5504), blk, 0, stream>>>((const float*)x, (const float*)W_DQ,
        (const float*)W_DKV, (const float*)W_UQ, (const float*)W_QR,
        (const float*)W_UK, (const float*)W_UV, xb);

    gemm128<<<dim3(4, 64), blk, 0, stream>>>(xb, wDQ,  cQ,  8192, 512, 1024, 0);
    gemm128<<<dim3(4, 64), blk, 0, stream>>>(xb, wDKV, cKV, 8192, 512, 1024, 0);
    gemm_bt<<<dim3(1, 128), blk, 0, stream>>>(xb, W_KR, kR, 8192, 32, 1024, 0, 0, 1, 0);
    gemm128<<<dim3(8, 64), blk, 0, stream>>>((short*)cQ,  wUQ, qC, 8192, 1024, 512, 0);
    gemm128<<<dim3(4, 64), blk, 0, stream>>>((short*)cQ,  wQR, qR, 8192, 512, 512, 0);
    gemm128<<<dim3(8, 64), blk, 0, stream>>>((short*)cKV, wUK, kC, 8192, 1024, 512, 0);
    gemm128<<<dim3(8, 64), blk, 0, stream>>>((short*)cKV, wUV, vT, 8192, 1024, 512, 1);
    rope_kernel<<<dim3(8192), blk, 0, stream>>>(qR, 2097152, 256);
    rope_kernel<<<dim3(512), blk, 0, stream>>>(kR, 131072, 16);
    mla_attn<<<dim3(32, 16, 4), blk, 0, stream>>>(qC, qR, kC, kR, vT, attn);
    cvt_f32_bf16<<<dim3(512), blk, 0, stream>>>((const float*)W_O, wO, 131072);
    gemm128<<<dim3(8, 64), blk, 0, stream>>>((short*)attn, wO, out, 8192, 1024, 1024, 2);
  } else {
    // ---------- small path: per-batch arena (unchanged fallback) ----------
    __hip_bfloat16* qc = ws;
    __hip_bfloat16* qr = ws + 2097152;
    __hip_bfloat16* kc = ws + 3145728;
    __hip_bfloat16* kr = ws + 5242880;
    __hip_bfloat16* F  = ws + 5308416;

    for (int b = 0; b < 4; b++) {
      unsigned long long xoff = (unsigned long long)b * 2048 * 1024;
      float* outb = out + (size_t)b * 2097152;
      __hip_bfloat16* vtb = (__hip_bfloat16*)outb;

      gemm_bt<<<dim3(8, 32), blk, 0, stream>>>(x, W_DQ,  F,  2048, 512, 1024, 0, 1, 1, xoff);
      gemm_bt<<<dim3(16, 32), blk, 0, stream>>>(F, W_UQ,  qc, 2048, 1024, 512, 0, 0, 1, 0);
      gemm_bt<<<dim3(8, 32), blk, 0, stream>>>(F, W_QR,  qr, 2048, 512, 512, 0, 0, 1, 0);
      gemm_bt<<<dim3(8, 32), blk, 0, stream>>>(x, W_DKV, F,  2048, 512, 1024, 0, 1, 1, xoff);
      gemm_bt<<<dim3(16, 32), blk, 0, stream>>>(F, W_UK,  kc, 2048, 1024, 512, 0, 0, 1, 0);
      gemm_bt<<<dim3(16, 32), blk, 0, stream>>>(F, W_UV,  vtb, 2048, 1024, 512, 1, 0, 1, 0);
      gemm_bt<<<dim3(1, 32), blk, 0, stream>>>(x, W_KR,  kr, 2048, 32, 1024, 0, 1, 1, xoff);
      rope_kernel<<<dim3(2048), blk, 0, stream>>>(qr, 524288, 256);
      rope_kernel<<<dim3(128), blk, 0, stream>>>(kr, 32768, 16);
      mla_attn<<<dim3(32, 16, 1), blk, 0, stream>>>(qc, qr, kc, kr, vtb, F);
      gemm_bt<<<dim3(16, 32), blk, 0, stream>>>(F, W_O, outb, 2048, 1024, 1024, 2, 0, 1, 0);
    }
  }
}

// Round 5
// 462.108 us; speedup vs baseline: 1.9652x; 1.0184x over previous
//
#include <hip/hip_runtime.h>
#include <hip/hip_bf16.h>

typedef short short8 __attribute__((ext_vector_type(8)));
typedef short short4v __attribute__((ext_vector_type(4)));
typedef float floatx4 __attribute__((ext_vector_type(4)));

__device__ __forceinline__ short f2bf(float x) {
  __hip_bfloat16 h = __float2bfloat16(x);
  return __builtin_bit_cast(short, h);
}

__device__ __forceinline__ short8 load8(const void* __restrict__ p, size_t idx, int f32) {
  if (f32) {
    const float* f = (const float*)p + idx;
    short8 r;
#pragma unroll
    for (int i = 0; i < 8; i++) r[i] = f2bf(f[i]);
    return r;
  }
  return *(const short8*)((const short*)p + idx);
}

// ---------- legacy 64x64 GEMM (small path + tiny N=32 GEMM) ----------
__global__ __launch_bounds__(256) void gemm_bt(
    const void* __restrict__ A,
    const void* __restrict__ Bm,
    void* __restrict__ C,
    int M, int N, int K, int omode,
    int af32, int bf32, unsigned long long aoff)
{
  __shared__ short As[64][72];
  __shared__ short Bs[64][72];
  const int tid  = threadIdx.x;
  const int wave = tid >> 6, lane = tid & 63;
  const int quad = lane >> 4, l15 = lane & 15;
  const int m0 = blockIdx.y * 64, n0 = blockIdx.x * 64;
  const int wr = (wave >> 1) * 32, wc = (wave & 1) * 32;

  floatx4 acc00 = {}, acc01 = {}, acc10 = {}, acc11 = {};

  const int r0 = tid >> 3, kc0 = (tid & 7) << 3;
  const int r1 = r0 + 32;

  for (int k0 = 0; k0 < K; k0 += 64) {
    __syncthreads();
    *(short8*)&As[r0][kc0] = load8(A, aoff + (size_t)(m0 + r0) * K + k0 + kc0, af32);
    *(short8*)&As[r1][kc0] = load8(A, aoff + (size_t)(m0 + r1) * K + k0 + kc0, af32);
    short8 bz = {};
    *(short8*)&Bs[r0][kc0] = (n0 + r0 < N) ? load8(Bm, (size_t)(n0 + r0) * K + k0 + kc0, bf32) : bz;
    *(short8*)&Bs[r1][kc0] = (n0 + r1 < N) ? load8(Bm, (size_t)(n0 + r1) * K + k0 + kc0, bf32) : bz;
    __syncthreads();
#pragma unroll
    for (int kk = 0; kk < 64; kk += 32) {
      short8 a0 = *(const short8*)&As[wr + l15][kk + quad * 8];
      short8 a1 = *(const short8*)&As[wr + 16 + l15][kk + quad * 8];
      short8 b0 = *(const short8*)&Bs[wc + l15][kk + quad * 8];
      short8 b1 = *(const short8*)&Bs[wc + 16 + l15][kk + quad * 8];
      acc00 = __builtin_amdgcn_mfma_f32_16x16x32_bf16(a0, b0, acc00, 0, 0, 0);
      acc01 = __builtin_amdgcn_mfma_f32_16x16x32_bf16(a0, b1, acc01, 0, 0, 0);
      acc10 = __builtin_amdgcn_mfma_f32_16x16x32_bf16(a1, b0, acc10, 0, 0, 0);
      acc11 = __builtin_amdgcn_mfma_f32_16x16x32_bf16(a1, b1, acc11, 0, 0, 0);
    }
  }

  floatx4 accs[2][2] = {{acc00, acc01}, {acc10, acc11}};
#pragma unroll
  for (int i = 0; i < 2; i++)
#pragma unroll
    for (int j = 0; j < 2; j++)
#pragma unroll
      for (int r = 0; r < 4; r++) {
        int row = m0 + wr + i * 16 + quad * 4 + r;
        int col = n0 + wc + j * 16 + l15;
        if (col < N) {
          float v = accs[i][j][r];
          if (omode == 2) {
            ((float*)C)[(size_t)row * N + col] = v;
          } else if (omode == 1) {
            ((__hip_bfloat16*)C)[(((size_t)(row >> 11) * 1024 + col) << 11) + (row & 2047)] =
                __float2bfloat16(v);
          } else {
            ((__hip_bfloat16*)C)[(size_t)row * N + col] = __float2bfloat16(v);
          }
        }
      }
}

// ---------- shared 128x128 GEMM body ----------
__device__ __forceinline__ void gemm128_body(
    const short* __restrict__ A,
    const short* __restrict__ Bm,
    void* __restrict__ C,
    int N, int K, int omode, int m0, int n0,
    short* As, short* Bs)
{
  const int tid  = threadIdx.x;
  const int wave = tid >> 6, lane = tid & 63;
  const int quad = lane >> 4, l15 = lane & 15;
  const int wr = (wave >> 1) * 64, wc = (wave & 1) * 64;

  floatx4 acc[4][4] = {};

  typedef __attribute__((address_space(3))) short lds_short;
  typedef __attribute__((address_space(1))) const void gbl_void;
  lds_short* Asl = (lds_short*)As;
  lds_short* Bsl = (lds_short*)Bs;

  for (int k0 = 0; k0 < K; k0 += 64) {
    __syncthreads();
#pragma unroll
    for (int it = 0; it < 4; it++) {
      int c = it * 256 + tid;
      int row = c >> 3, s = c & 7;
      int gcol = ((s ^ (row & 7)) << 3);
      const short* ga = &A[(size_t)(m0 + row) * K + k0 + gcol];
      const short* gb = &Bm[(size_t)(n0 + row) * K + k0 + gcol];
      __builtin_amdgcn_global_load_lds((gbl_void*)ga,
          (__attribute__((address_space(3))) void*)(Asl + (size_t)c * 8), 16, 0, 0);
      __builtin_amdgcn_global_load_lds((gbl_void*)gb,
          (__attribute__((address_space(3))) void*)(Bsl + (size_t)c * 8), 16, 0, 0);
    }
    __syncthreads();
#pragma unroll
    for (int kk = 0; kk < 64; kk += 32) {
      const int qb = (kk >> 3) + quad;
      short8 af[4], bf[4];
#pragma unroll
      for (int i = 0; i < 4; i++) {
        int ar = wr + i * 16 + l15;
        af[i] = *(const short8*)&As[ar * 64 + ((qb ^ (ar & 7)) << 3)];
        int br = wc + i * 16 + l15;
        bf[i] = *(const short8*)&Bs[br * 64 + ((qb ^ (br & 7)) << 3)];
      }
      __builtin_amdgcn_s_setprio(1);
#pragma unroll
      for (int i = 0; i < 4; i++)
#pragma unroll
        for (int j = 0; j < 4; j++)
          acc[i][j] = __builtin_amdgcn_mfma_f32_16x16x32_bf16(af[i], bf[j], acc[i][j], 0, 0, 0);
      __builtin_amdgcn_s_setprio(0);
    }
  }

#pragma unroll
  for (int i = 0; i < 4; i++)
#pragma unroll
    for (int j = 0; j < 4; j++)
#pragma unroll
      for (int r = 0; r < 4; r++) {
        int row = m0 + wr + i * 16 + quad * 4 + r;
        int col = n0 + wc + j * 16 + l15;
        float v = acc[i][j][r];
        if (omode == 2) {
          ((float*)C)[(size_t)row * N + col] = v;
        } else if (omode == 1) {
          ((__hip_bfloat16*)C)[(((size_t)(row >> 11) * 1024 + col) << 11) + (row & 2047)] =
              __float2bfloat16(v);
        } else {
          ((__hip_bfloat16*)C)[(size_t)row * N + col] = __float2bfloat16(v);
        }
      }
}

__global__ __launch_bounds__(256) void gemm128(
    const short* __restrict__ A,
    const short* __restrict__ Bm,
    void* __restrict__ C,
    int M, int N, int K, int omode)
{
  __shared__ short As[128 * 64];
  __shared__ short Bs[128 * 64];
  gemm128_body(A, Bm, C, N, K, omode, blockIdx.y * 128, blockIdx.x * 128, As, Bs);
}

// Two GEMMs sharing A, fused into one launch for >=2 blocks/CU occupancy.
// blockIdx.x < nb1 -> (B1,C1,N1,omode1); else -> (B2,C2,N2,omode2).
__global__ __launch_bounds__(256) void gemm128_dual(
    const short* __restrict__ A,
    const short* __restrict__ B1, void* __restrict__ C1, int N1, int omode1, int nb1,
    const short* __restrict__ B2, void* __restrict__ C2, int N2, int omode2,
    int M, int K)
{
  __shared__ short As[128 * 64];
  __shared__ short Bs[128 * 64];
  const int bx = blockIdx.x;
  if (bx < nb1)
    gemm128_body(A, B1, C1, N1, K, omode1, blockIdx.y * 128, bx * 128, As, Bs);
  else
    gemm128_body(A, B2, C2, N2, K, omode2, blockIdx.y * 128, (bx - nb1) * 128, As, Bs);
}

// ---------- f32 -> bf16 converters ----------
__device__ __forceinline__ void cvt_chunk(const float* __restrict__ s, short* __restrict__ d) {
  float4 u = ((const float4*)s)[0];
  float4 v = ((const float4*)s)[1];
  short8 o;
  o[0] = f2bf(u.x); o[1] = f2bf(u.y); o[2] = f2bf(u.z); o[3] = f2bf(u.w);
  o[4] = f2bf(v.x); o[5] = f2bf(v.y); o[6] = f2bf(v.z); o[7] = f2bf(v.w);
  *(short8*)d = o;
}

__global__ __launch_bounds__(256) void cvt_all(
    const float* __restrict__ x,    const float* __restrict__ wdq,
    const float* __restrict__ wdkv, const float* __restrict__ wuq,
    const float* __restrict__ wqr,  const float* __restrict__ wuk,
    const float* __restrict__ wuv,  short* __restrict__ dst)
{
  int g = blockIdx.x * 256 + threadIdx.x;
  const float* src; int loc;
  if      (g < 1048576) { src = x;    loc = g; }
  else if (g < 1114112) { src = wdq;  loc = g - 1048576; }
  else if (g < 1179648) { src = wdkv; loc = g - 1114112; }
  else if (g < 1245184) { src = wuq;  loc = g - 1179648; }
  else if (g < 1277952) { src = wqr;  loc = g - 1245184; }
  else if (g < 1343488) { src = wuk;  loc = g - 1277952; }
  else                  { src = wuv;  loc = g - 1343488; }
  cvt_chunk(src + (size_t)loc * 8, dst + (size_t)g * 8);
}

__global__ __launch_bounds__(256) void cvt_f32_bf16(
    const float* __restrict__ src, short* __restrict__ dst, int nchunk)
{
  int g = blockIdx.x * 256 + threadIdx.x;
  if (g >= nchunk) return;
  cvt_chunk(src + (size_t)g * 8, dst + (size_t)g * 8);
}

// In-place interleaved RoPE on internal bf16 buffers.
__global__ __launch_bounds__(256) void rope_kernel(__hip_bfloat16* p, int n_pairs, int ppp) {
  int g = blockIdx.x * 256 + threadIdx.x;
  if (g >= n_pairs) return;
  int i = g & 15;
  int pos = (g / ppp) & 2047;
  float inv_freq = powf(10000.0f, -(float)i * (1.0f / 16.0f));
  float ang = (float)pos * inv_freq;
  float sn, cs;
  sincosf(ang, &sn, &cs);
  float x1 = __bfloat162float(p[2 * g]);
  float x2 = __bfloat162float(p[2 * g + 1]);
  p[2 * g]     = __float2bfloat16(x1 * cs - x2 * sn);
  p[2 * g + 1] = __float2bfloat16(x1 * sn + x2 * cs);
}

// Batched causal flash attention, KVBLK=64, fixed-max softmax,
// TRANSPOSED dataflow: S^T = mfma(K,Q) keeps P^T lane-local (q = lane&15),
// O^T = mfma(V^T, P^T) consumes P straight from registers -> no P LDS
// round-trip, coalesced b64 O stores, 2-shfl final reduction.
// Key permutation within each 32-key half (kappa = quad*8+i <-> key =
// (i>>2)*16+quad*4+(i&3)) is applied identically to the V-fragment (two b64
// reads) and the P-fragment (ps[j][r] packing), so the mfma sums match.
__global__ __launch_bounds__(256) void mla_attn(
    const __hip_bfloat16* __restrict__ qC,
    const __hip_bfloat16* __restrict__ qR,
    const __hip_bfloat16* __restrict__ kC,
    const __hip_bfloat16* __restrict__ kR,
    const __hip_bfloat16* __restrict__ vT,
    __hip_bfloat16* __restrict__ O)
{
  const int tid  = threadIdx.x;
  const int wave = tid >> 6, lane = tid & 63;
  const int quad = lane >> 4, l15 = lane & 15;
  const int head = blockIdx.y;
  const int q0 = (gridDim.x - 1 - blockIdx.x) * 64;
  const int b = blockIdx.z;

  __shared__ short Ks[64][104];
  __shared__ short Vt[64][72];

  const short* qCs = reinterpret_cast<const short*>(qC) + (size_t)b * 2097152;
  const short* qRs = reinterpret_cast<const short*>(qR) + (size_t)b * 1048576;
  const short* kCs = reinterpret_cast<const short*>(kC) + (size_t)b * 2097152;
  const short* kRs = reinterpret_cast<const short*>(kR) + (size_t)b * 65536;
  const short* Vs  = reinterpret_cast<const short*>(vT) + (size_t)b * 2097152;
  short* Ob = reinterpret_cast<short*>(O) + (size_t)b * 2097152;

  // Q fragments (B-operand now; layout [n=l15][k=quad*8+i] is identical)
  const int qrow = q0 + wave * 16 + l15;
  const size_t qcbase = ((size_t)qrow * 16 + head) * 64;
  const size_t qrbase = ((size_t)qrow * 16 + head) * 32;
  short8 aq0 = *(const short8*)&qCs[qcbase + quad * 8];
  short8 aq1 = *(const short8*)&qCs[qcbase + 32 + quad * 8];
  short8 aq2 = *(const short8*)&qRs[qrbase + quad * 8];

  float lpart = 0.f;            // per-lane partial sum for q = qrow
  floatx4 accO[4] = {};         // accO[c][r] = O^T[dv=c*16+quad*4+r][q=qrow]

  const float SC2 = 0.14724445f;   // (1/sqrt(96)) * log2(e)
  const float CL2 = 11.7795557f;   // (80/sqrt(96)) * log2(e)
  const int qpos = q0 + wave * 16 + l15;

  const int nkt = (q0 >> 6) + 1;
  for (int kt = 0; kt < nkt; kt++) {
    const int k0 = kt * 64;
    const bool diag = (kt == nkt - 1);
    __syncthreads();
    {
#pragma unroll
      for (int it = 0; it < 3; it++) {
        int c = tid + it * 256;
        int key = c / 12, seg = c - key * 12;
        short8 kv;
        if (seg < 8) kv = *(const short8*)&kCs[((size_t)(k0 + key) * 16 + head) * 64 + seg * 8];
        else         kv = *(const short8*)&kRs[(size_t)(k0 + key) * 32 + (seg - 8) * 8];
        *(short8*)&Ks[key][seg * 8] = kv;
      }
    }
    {
#pragma unroll
      for (int it = 0; it < 2; it++) {
        int c = tid + it * 256;
        int dv = c >> 3, kc = (c & 7) << 3;
        short8 vv = *(const short8*)&Vs[((size_t)(head * 64 + dv)) * 2048 + k0 + kc];
        *(short8*)&Vt[dv][kc] = vv;
      }
    }
    __syncthreads();

    float ps[4][4];
    __builtin_amdgcn_s_setprio(1);
#pragma unroll
    for (int j = 0; j < 4; j++) {
      short8 kf0 = *(const short8*)&Ks[j * 16 + l15][quad * 8];
      short8 kf1 = *(const short8*)&Ks[j * 16 + l15][32 + quad * 8];
      short8 kf2 = *(const short8*)&Ks[j * 16 + l15][64 + quad * 8];
      floatx4 s = {};
      s = __builtin_amdgcn_mfma_f32_16x16x32_bf16(kf0, aq0, s, 0, 0, 0);
      s = __builtin_amdgcn_mfma_f32_16x16x32_bf16(kf1, aq1, s, 0, 0, 0);
      s = __builtin_amdgcn_mfma_f32_16x16x32_bf16(kf2, aq2, s, 0, 0, 0);
      // s[r] = S^T[k = k0+j*16+quad*4+r][q = qpos]
#pragma unroll
      for (int r = 0; r < 4; r++) {
        float t = fminf(fmaxf(s[r], -80.f), 80.f) * SC2 - CL2;
        if (diag) {
          const int kpos = k0 + j * 16 + quad * 4 + r;
          if (kpos > qpos) t = -12000.f;   // exp2 -> exactly 0
        }
        float p = exp2f(t);
        ps[j][r] = p;
        lpart += p;
      }
    }
    __builtin_amdgcn_s_setprio(0);

    // P^T fragments: Pb[h][i] = P^T[key=(i>>2)*16+quad*4+(i&3)+h*32][q]
    short8 Pb0, Pb1;
#pragma unroll
    for (int i = 0; i < 4; i++) {
      Pb0[i]     = f2bf(ps[0][i]);
      Pb0[i + 4] = f2bf(ps[1][i]);
      Pb1[i]     = f2bf(ps[2][i]);
      Pb1[i + 4] = f2bf(ps[3][i]);
    }
    __builtin_amdgcn_s_setprio(1);
#pragma unroll
    for (int c = 0; c < 4; c++) {
      const short* vrow = &Vt[c * 16 + l15][0];
      short4v v00 = *(const short4v*)&vrow[quad * 4];
      short4v v01 = *(const short4v*)&vrow[16 + quad * 4];
      short4v v10 = *(const short4v*)&vrow[32 + quad * 4];
      short4v v11 = *(const short4v*)&vrow[48 + quad * 4];
      short8 a0 = __builtin_shufflevector(v00, v01, 0, 1, 2, 3, 4, 5, 6, 7);
      short8 a1 = __builtin_shufflevector(v10, v11, 0, 1, 2, 3, 4, 5, 6, 7);
      accO[c] = __builtin_amdgcn_mfma_f32_16x16x32_bf16(a0, Pb0, accO[c], 0, 0, 0);
      accO[c] = __builtin_amdgcn_mfma_f32_16x16x32_bf16(a1, Pb1, accO[c], 0, 0, 0);
    }
    __builtin_amdgcn_s_setprio(0);
  }

  float rs = lpart;
  rs += __shfl_xor(rs, 16);
  rs += __shfl_xor(rs, 32);
  float inv = (rs > 0.f) ? 1.f / rs : 0.f;
  const size_t obase = (size_t)qpos * 1024 + head * 64;
#pragma unroll
  for (int c = 0; c < 4; c++) {
    short4v o;
#pragma unroll
    for (int r = 0; r < 4; r++) o[r] = f2bf(accO[c][r] * inv);
    *(short4v*)&Ob[obase + c * 16 + quad * 4] = o;
  }
}

extern "C" void kernel_launch(void* const* d_in, const int* in_sizes, int n_in,
                              void* d_out, int out_size, void* d_ws, size_t ws_size,
                              hipStream_t stream) {
  const void* x     = d_in[0];
  const void* W_DQ  = d_in[1];
  const void* W_UQ  = d_in[2];
  const void* W_QR  = d_in[3];
  const void* W_DKV = d_in[4];
  const void* W_UK  = d_in[5];
  const void* W_UV  = d_in[6];
  const void* W_KR  = d_in[7];
  const void* W_O   = d_in[8];
  float* out = (float*)d_out;
  __hip_bfloat16* ws = (__hip_bfloat16*)d_ws;

  dim3 blk(256);

  if (ws_size >= (size_t)76021760) {
    // ---------- big path ----------
    __hip_bfloat16* cQ   = ws;                 // 8192x512
    __hip_bfloat16* cKV  = ws + 4194304;       // 8192x512
    __hip_bfloat16* attn = ws;                 // 8192x1024 (overlays dead cQ+cKV)
    __hip_bfloat16* qC   = ws + 8388608;       // (B,S,H,64)
    __hip_bfloat16* qR   = ws + 16777216;      // (B,S,H,32)
    __hip_bfloat16* kC   = ws + 20971520;      // (B,S,H,64)
    __hip_bfloat16* vT   = ws + 29360128;      // (B,1024,2048)
    __hip_bfloat16* kR   = ws + 37748736;      // (B,S,32)

    // bf16 scratch inside d_out (dead until final GEMM overwrites it):
    short* xb   = (short*)out;                 // 8,388,608 el (x as bf16)
    short* wb   = xb + 8388608;                // packed weights
    short* wDQ  = wb;                          // 524288
    short* wDKV = wb + 524288;                 // 524288
    short* wUQ  = wb + 1048576;                // 524288
    short* wQR  = wb + 1572864;                // 262144
    short* wUK  = wb + 1835008;                // 524288
    short* wUV  = wb + 2359296;                // 524288
    short* wO   = (short*)qC;                  // W_O bf16, written AFTER attn (qC dead)

    cvt_all<<<dim3(5504), blk, 0, stream>>>((const float*)x, (const float*)W_DQ,
        (const float*)W_DKV, (const float*)W_UQ, (const float*)W_QR,
        (const float*)W_UK, (const float*)W_UV, xb);

    // Fused same-A GEMM pairs: 512 / 768 / 1024 blocks = 2-4 blocks/CU.
    gemm128_dual<<<dim3(8, 64), blk, 0, stream>>>(xb,
        wDQ, cQ, 512, 0, 4, wDKV, cKV, 512, 0, 8192, 1024);
    gemm_bt<<<dim3(1, 128), blk, 0, stream>>>(xb, W_KR, kR, 8192, 32, 1024, 0, 0, 1, 0);
    gemm128_dual<<<dim3(12, 64), blk, 0, stream>>>((short*)cQ,
        wUQ, qC, 1024, 0, 8, wQR, qR, 512, 0, 8192, 512);
    gemm128_dual<<<dim3(16, 64), blk, 0, stream>>>((short*)cKV,
        wUK, kC, 1024, 0, 8, wUV, vT, 1024, 1, 8192, 512);
    rope_kernel<<<dim3(8192), blk, 0, stream>>>(qR, 2097152, 256);
    rope_kernel<<<dim3(512), blk, 0, stream>>>(kR, 131072, 16);
    mla_attn<<<dim3(32, 16, 4), blk, 0, stream>>>(qC, qR, kC, kR, vT, attn);
    cvt_f32_bf16<<<dim3(512), blk, 0, stream>>>((const float*)W_O, wO, 131072);
    gemm128<<<dim3(8, 64), blk, 0, stream>>>((short*)attn, wO, out, 8192, 1024, 1024, 2);
  } else {
    // ---------- small path: per-batch arena (unchanged fallback) ----------
    __hip_bfloat16* qc = ws;
    __hip_bfloat16* qr = ws + 2097152;
    __hip_bfloat16* kc = ws + 3145728;
    __hip_bfloat16* kr = ws + 5242880;
    __hip_bfloat16* F  = ws + 5308416;

    for (int b = 0; b < 4; b++) {
      unsigned long long xoff = (unsigned long long)b * 2048 * 1024;
      float* outb = out + (size_t)b * 2097152;
      __hip_bfloat16* vtb = (__hip_bfloat16*)outb;

      gemm_bt<<<dim3(8, 32), blk, 0, stream>>>(x, W_DQ,  F,  2048, 512, 1024, 0, 1, 1, xoff);
      gemm_bt<<<dim3(16, 32), blk, 0, stream>>>(F, W_UQ,  qc, 2048, 1024, 512, 0, 0, 1, 0);
      gemm_bt<<<dim3(8, 32), blk, 0, stream>>>(F, W_QR,  qr, 2048, 512, 512, 0, 0, 1, 0);
      gemm_bt<<<dim3(8, 32), blk, 0, stream>>>(x, W_DKV, F,  2048, 512, 1024, 0, 1, 1, xoff);
      gemm_bt<<<dim3(16, 32), blk, 0, stream>>>(F, W_UK,  kc, 2048, 1024, 512, 0, 0, 1, 0);
      gemm_bt<<<dim3(16, 32), blk, 0, stream>>>(F, W_UV,  vtb, 2048, 1024, 512, 1, 0, 1, 0);
      gemm_bt<<<dim3(1, 32), blk, 0, stream>>>(x, W_KR,  kr, 2048, 32, 1024, 0, 1, 1, xoff);
      rope_kernel<<<dim3(2048), blk, 0, stream>>>(qr, 524288, 256);
      rope_kernel<<<dim3(128), blk, 0, stream>>>(kr, 32768, 16);
      mla_attn<<<dim3(32, 16, 1), blk, 0, stream>>>(qc, qr, kc, kr, vtb, F);
      gemm_bt<<<dim3(16, 32), blk, 0, stream>>>(F, W_O, outb, 2048, 1024, 1024, 2, 0, 1, 0);
    }
  }
}

// Round 6
// 407.384 us; speedup vs baseline: 2.2292x; 1.1343x over previous
//
#include <hip/hip_runtime.h>
#include <hip/hip_bf16.h>

typedef short short8 __attribute__((ext_vector_type(8)));
typedef short short4v __attribute__((ext_vector_type(4)));
typedef float floatx4 __attribute__((ext_vector_type(4)));

__device__ __forceinline__ short f2bf(float x) {
  __hip_bfloat16 h = __float2bfloat16(x);
  return __builtin_bit_cast(short, h);
}

__device__ __forceinline__ short8 load8(const void* __restrict__ p, size_t idx, int f32) {
  if (f32) {
    const float* f = (const float*)p + idx;
    short8 r;
#pragma unroll
    for (int i = 0; i < 8; i++) r[i] = f2bf(f[i]);
    return r;
  }
  return *(const short8*)((const short*)p + idx);
}

// ---------- legacy 64x64 GEMM (small path only) ----------
__global__ __launch_bounds__(256) void gemm_bt(
    const void* __restrict__ A,
    const void* __restrict__ Bm,
    void* __restrict__ C,
    int M, int N, int K, int omode,
    int af32, int bf32, unsigned long long aoff)
{
  __shared__ short As[64][72];
  __shared__ short Bs[64][72];
  const int tid  = threadIdx.x;
  const int wave = tid >> 6, lane = tid & 63;
  const int quad = lane >> 4, l15 = lane & 15;
  const int m0 = blockIdx.y * 64, n0 = blockIdx.x * 64;
  const int wr = (wave >> 1) * 32, wc = (wave & 1) * 32;

  floatx4 acc00 = {}, acc01 = {}, acc10 = {}, acc11 = {};

  const int r0 = tid >> 3, kc0 = (tid & 7) << 3;
  const int r1 = r0 + 32;

  for (int k0 = 0; k0 < K; k0 += 64) {
    __syncthreads();
    *(short8*)&As[r0][kc0] = load8(A, aoff + (size_t)(m0 + r0) * K + k0 + kc0, af32);
    *(short8*)&As[r1][kc0] = load8(A, aoff + (size_t)(m0 + r1) * K + k0 + kc0, af32);
    short8 bz = {};
    *(short8*)&Bs[r0][kc0] = (n0 + r0 < N) ? load8(Bm, (size_t)(n0 + r0) * K + k0 + kc0, bf32) : bz;
    *(short8*)&Bs[r1][kc0] = (n0 + r1 < N) ? load8(Bm, (size_t)(n0 + r1) * K + k0 + kc0, bf32) : bz;
    __syncthreads();
#pragma unroll
    for (int kk = 0; kk < 64; kk += 32) {
      short8 a0 = *(const short8*)&As[wr + l15][kk + quad * 8];
      short8 a1 = *(const short8*)&As[wr + 16 + l15][kk + quad * 8];
      short8 b0 = *(const short8*)&Bs[wc + l15][kk + quad * 8];
      short8 b1 = *(const short8*)&Bs[wc + 16 + l15][kk + quad * 8];
      acc00 = __builtin_amdgcn_mfma_f32_16x16x32_bf16(a0, b0, acc00, 0, 0, 0);
      acc01 = __builtin_amdgcn_mfma_f32_16x16x32_bf16(a0, b1, acc01, 0, 0, 0);
      acc10 = __builtin_amdgcn_mfma_f32_16x16x32_bf16(a1, b0, acc10, 0, 0, 0);
      acc11 = __builtin_amdgcn_mfma_f32_16x16x32_bf16(a1, b1, acc11, 0, 0, 0);
    }
  }

  floatx4 accs[2][2] = {{acc00, acc01}, {acc10, acc11}};
#pragma unroll
  for (int i = 0; i < 2; i++)
#pragma unroll
    for (int j = 0; j < 2; j++)
#pragma unroll
      for (int r = 0; r < 4; r++) {
        int row = m0 + wr + i * 16 + quad * 4 + r;
        int col = n0 + wc + j * 16 + l15;
        if (col < N) {
          float v = accs[i][j][r];
          if (omode == 2) {
            ((float*)C)[(size_t)row * N + col] = v;
          } else if (omode == 1) {
            ((__hip_bfloat16*)C)[(((size_t)(row >> 11) * 1024 + col) << 11) + (row & 2047)] =
                __float2bfloat16(v);
          } else {
            ((__hip_bfloat16*)C)[(size_t)row * N + col] = __float2bfloat16(v);
          }
        }
      }
}

// ---------- shared 128x128 GEMM body (global_load_lds + XOR swizzle) ----------
// nB: valid B rows; staging clamps to nB-1 (results for col>=N are discarded
// by the col<N store guard).
__device__ __forceinline__ void gemm128_body(
    const short* __restrict__ A,
    const short* __restrict__ Bm,
    void* __restrict__ C,
    int N, int K, int omode, int m0, int n0, int nB,
    short* As, short* Bs)
{
  const int tid  = threadIdx.x;
  const int wave = tid >> 6, lane = tid & 63;
  const int quad = lane >> 4, l15 = lane & 15;
  const int wr = (wave >> 1) * 64, wc = (wave & 1) * 64;

  floatx4 acc[4][4] = {};

  typedef __attribute__((address_space(3))) short lds_short;
  typedef __attribute__((address_space(1))) const void gbl_void;
  lds_short* Asl = (lds_short*)As;
  lds_short* Bsl = (lds_short*)Bs;

  for (int k0 = 0; k0 < K; k0 += 64) {
    __syncthreads();
#pragma unroll
    for (int it = 0; it < 4; it++) {
      int c = it * 256 + tid;
      int row = c >> 3, s = c & 7;
      int gcol = ((s ^ (row & 7)) << 3);
      int brow = n0 + row; if (brow > nB - 1) brow = nB - 1;
      const short* ga = &A[(size_t)(m0 + row) * K + k0 + gcol];
      const short* gb = &Bm[(size_t)brow * K + k0 + gcol];
      __builtin_amdgcn_global_load_lds((gbl_void*)ga,
          (__attribute__((address_space(3))) void*)(Asl + (size_t)c * 8), 16, 0, 0);
      __builtin_amdgcn_global_load_lds((gbl_void*)gb,
          (__attribute__((address_space(3))) void*)(Bsl + (size_t)c * 8), 16, 0, 0);
    }
    __syncthreads();
#pragma unroll
    for (int kk = 0; kk < 64; kk += 32) {
      const int qb = (kk >> 3) + quad;
      short8 af[4], bf[4];
#pragma unroll
      for (int i = 0; i < 4; i++) {
        int ar = wr + i * 16 + l15;
        af[i] = *(const short8*)&As[ar * 64 + ((qb ^ (ar & 7)) << 3)];
        int br = wc + i * 16 + l15;
        bf[i] = *(const short8*)&Bs[br * 64 + ((qb ^ (br & 7)) << 3)];
      }
      __builtin_amdgcn_s_setprio(1);
#pragma unroll
      for (int i = 0; i < 4; i++)
#pragma unroll
        for (int j = 0; j < 4; j++)
          acc[i][j] = __builtin_amdgcn_mfma_f32_16x16x32_bf16(af[i], bf[j], acc[i][j], 0, 0, 0);
      __builtin_amdgcn_s_setprio(0);
    }
  }

#pragma unroll
  for (int i = 0; i < 4; i++)
#pragma unroll
    for (int j = 0; j < 4; j++)
#pragma unroll
      for (int r = 0; r < 4; r++) {
        int row = m0 + wr + i * 16 + quad * 4 + r;
        int col = n0 + wc + j * 16 + l15;
        if (col < N) {
          float v = acc[i][j][r];
          if (omode == 2) {
            ((float*)C)[(size_t)row * N + col] = v;
          } else if (omode == 1) {
            ((__hip_bfloat16*)C)[(((size_t)(row >> 11) * 1024 + col) << 11) + (row & 2047)] =
                __float2bfloat16(v);
          } else {
            ((__hip_bfloat16*)C)[(size_t)row * N + col] = __float2bfloat16(v);
          }
        }
      }
}

__global__ __launch_bounds__(256) void gemm128(
    const short* __restrict__ A,
    const short* __restrict__ Bm,
    void* __restrict__ C,
    int M, int N, int K, int omode)
{
  __shared__ short As[128 * 64];
  __shared__ short Bs[128 * 64];
  gemm128_body(A, Bm, C, N, K, omode, blockIdx.y * 128, blockIdx.x * 128, N, As, Bs);
}

// Up to 4 GEMM segments (possibly different A) fused into one launch.
// blockIdx.x selects the segment via nb0..nb2 cascade (block-uniform).
__global__ __launch_bounds__(256) void gemm128_multi(
    const short* A0, const short* B0, void* C0, int N0, int om0, int nb0, int nB0,
    const short* A1, const short* B1, void* C1, int N1, int om1, int nb1, int nB1,
    const short* A2, const short* B2, void* C2, int N2, int om2, int nb2, int nB2,
    const short* A3, const short* B3, void* C3, int N3, int om3, int nB3,
    int K)
{
  __shared__ short As[128 * 64];
  __shared__ short Bs[128 * 64];
  int bx = blockIdx.x;
  const short* A = A0; const short* Bm = B0; void* C = C0;
  int N = N0, om = om0, nB = nB0;
  if (bx >= nb0) {
    bx -= nb0; A = A1; Bm = B1; C = C1; N = N1; om = om1; nB = nB1;
    if (bx >= nb1) {
      bx -= nb1; A = A2; Bm = B2; C = C2; N = N2; om = om2; nB = nB2;
      if (bx >= nb2) {
        bx -= nb2; A = A3; Bm = B3; C = C3; N = N3; om = om3; nB = nB3;
      }
    }
  }
  gemm128_body(A, Bm, C, N, K, om, blockIdx.y * 128, bx * 128, nB, As, Bs);
}

// ---------- f32 -> bf16 converters ----------
__device__ __forceinline__ void cvt_chunk(const float* __restrict__ s, short* __restrict__ d) {
  float4 u = ((const float4*)s)[0];
  float4 v = ((const float4*)s)[1];
  short8 o;
  o[0] = f2bf(u.x); o[1] = f2bf(u.y); o[2] = f2bf(u.z); o[3] = f2bf(u.w);
  o[4] = f2bf(v.x); o[5] = f2bf(v.y); o[6] = f2bf(v.z); o[7] = f2bf(v.w);
  *(short8*)d = o;
}

// x + 7 weights (incl. W_KR), packed contiguously into dst (chunk = 8 elems).
__global__ __launch_bounds__(256) void cvt_all(
    const float* __restrict__ x,    const float* __restrict__ wdq,
    const float* __restrict__ wdkv, const float* __restrict__ wuq,
    const float* __restrict__ wqr,  const float* __restrict__ wuk,
    const float* __restrict__ wuv,  const float* __restrict__ wkr,
    short* __restrict__ dst)
{
  int g = blockIdx.x * 256 + threadIdx.x;
  const float* src; int loc;
  if      (g < 1048576) { src = x;    loc = g; }
  else if (g < 1114112) { src = wdq;  loc = g - 1048576; }
  else if (g < 1179648) { src = wdkv; loc = g - 1114112; }
  else if (g < 1245184) { src = wuq;  loc = g - 1179648; }
  else if (g < 1277952) { src = wqr;  loc = g - 1245184; }
  else if (g < 1343488) { src = wuk;  loc = g - 1277952; }
  else if (g < 1409024) { src = wuv;  loc = g - 1343488; }
  else                  { src = wkr;  loc = g - 1409024; }
  cvt_chunk(src + (size_t)loc * 8, dst + (size_t)g * 8);
}

__global__ __launch_bounds__(256) void cvt_f32_bf16(
    const float* __restrict__ src, short* __restrict__ dst, int nchunk)
{
  int g = blockIdx.x * 256 + threadIdx.x;
  if (g >= nchunk) return;
  cvt_chunk(src + (size_t)g * 8, dst + (size_t)g * 8);
}

// In-place interleaved RoPE on internal bf16 buffers.
__global__ __launch_bounds__(256) void rope_kernel(__hip_bfloat16* p, int n_pairs, int ppp) {
  int g = blockIdx.x * 256 + threadIdx.x;
  if (g >= n_pairs) return;
  int i = g & 15;
  int pos = (g / ppp) & 2047;
  float inv_freq = exp2f((float)i * -0.83048202f);  // 10000^(-i/16)
  float ang = (float)pos * inv_freq;
  float sn, cs;
  sincosf(ang, &sn, &cs);
  float x1 = __bfloat162float(p[2 * g]);
  float x2 = __bfloat162float(p[2 * g + 1]);
  p[2 * g]     = __float2bfloat16(x1 * cs - x2 * sn);
  p[2 * g + 1] = __float2bfloat16(x1 * sn + x2 * cs);
}

// Batched causal flash attention, KVBLK=64, fixed-max softmax, transposed
// dataflow (S^T = mfma(K,Q), O^T = mfma(V,P^T), P never leaves registers).
// V is staged into LDS PRE-PERMUTED by the kappa map so each PV A-fragment
// is a single b128 read:  p(key) = (key&32) + ((key>>2)&3)*8 + ((key>>4)&1)*4
// + (key&3);  read a0 = Vt[dv][quad*8..+7], a1 = Vt[dv][32+quad*8..+7].
__global__ __launch_bounds__(256) void mla_attn(
    const __hip_bfloat16* __restrict__ qC,
    const __hip_bfloat16* __restrict__ qR,
    const __hip_bfloat16* __restrict__ kC,
    const __hip_bfloat16* __restrict__ kR,
    const __hip_bfloat16* __restrict__ vT,
    __hip_bfloat16* __restrict__ O)
{
  const int tid  = threadIdx.x;
  const int wave = tid >> 6, lane = tid & 63;
  const int quad = lane >> 4, l15 = lane & 15;
  const int head = blockIdx.y;
  const int q0 = (gridDim.x - 1 - blockIdx.x) * 64;
  const int b = blockIdx.z;

  __shared__ short Ks[64][104];
  __shared__ short Vt[64][72];

  const short* qCs = reinterpret_cast<const short*>(qC) + (size_t)b * 2097152;
  const short* qRs = reinterpret_cast<const short*>(qR) + (size_t)b * 1048576;
  const short* kCs = reinterpret_cast<const short*>(kC) + (size_t)b * 2097152;
  const short* kRs = reinterpret_cast<const short*>(kR) + (size_t)b * 65536;
  const short* Vs  = reinterpret_cast<const short*>(vT) + (size_t)b * 2097152;
  short* Ob = reinterpret_cast<short*>(O) + (size_t)b * 2097152;

  const int qrow = q0 + wave * 16 + l15;
  const size_t qcbase = ((size_t)qrow * 16 + head) * 64;
  const size_t qrbase = ((size_t)qrow * 16 + head) * 32;
  short8 aq0 = *(const short8*)&qCs[qcbase + quad * 8];
  short8 aq1 = *(const short8*)&qCs[qcbase + 32 + quad * 8];
  short8 aq2 = *(const short8*)&qRs[qrbase + quad * 8];

  float lpart = 0.f;
  floatx4 accO[4] = {};

  const float SC2 = 0.14724445f;   // (1/sqrt(96)) * log2(e)
  const float CL2 = 11.7795557f;   // (80/sqrt(96)) * log2(e)
  const int qpos = q0 + wave * 16 + l15;

  const int nkt = (q0 >> 6) + 1;
  for (int kt = 0; kt < nkt; kt++) {
    const int k0 = kt * 64;
    const bool diag = (kt == nkt - 1);
    __syncthreads();
    {
#pragma unroll
      for (int it = 0; it < 3; it++) {
        int c = tid + it * 256;
        int key = c / 12, seg = c - key * 12;
        short8 kv;
        if (seg < 8) kv = *(const short8*)&kCs[((size_t)(k0 + key) * 16 + head) * 64 + seg * 8];
        else         kv = *(const short8*)&kRs[(size_t)(k0 + key) * 32 + (seg - 8) * 8];
        *(short8*)&Ks[key][seg * 8] = kv;
      }
    }
    {
#pragma unroll
      for (int it = 0; it < 2; it++) {
        int c = tid + it * 256;
        int dv = c >> 3, kc = (c & 7) << 3;
        short8 vv = *(const short8*)&Vs[((size_t)(head * 64 + dv)) * 2048 + k0 + kc];
        int g = kc & 31, h32 = kc & 32;
        int qk = (g >> 2) & 3;          // 0 or 2
        int hi = (g >> 4) & 1;
        int pA = h32 + qk * 8 + hi * 4;
        int pB = h32 + (qk + 1) * 8 + hi * 4;
        short4v lo4 = {vv[0], vv[1], vv[2], vv[3]};
        short4v hi4 = {vv[4], vv[5], vv[6], vv[7]};
        *(short4v*)&Vt[dv][pA] = lo4;
        *(short4v*)&Vt[dv][pB] = hi4;
      }
    }
    __syncthreads();

    float ps[4][4];
    __builtin_amdgcn_s_setprio(1);
#pragma unroll
    for (int j = 0; j < 4; j++) {
      short8 kf0 = *(const short8*)&Ks[j * 16 + l15][quad * 8];
      short8 kf1 = *(const short8*)&Ks[j * 16 + l15][32 + quad * 8];
      short8 kf2 = *(const short8*)&Ks[j * 16 + l15][64 + quad * 8];
      floatx4 s = {};
      s = __builtin_amdgcn_mfma_f32_16x16x32_bf16(kf0, aq0, s, 0, 0, 0);
      s = __builtin_amdgcn_mfma_f32_16x16x32_bf16(kf1, aq1, s, 0, 0, 0);
      s = __builtin_amdgcn_mfma_f32_16x16x32_bf16(kf2, aq2, s, 0, 0, 0);
#pragma unroll
      for (int r = 0; r < 4; r++) {
        float t = fminf(fmaxf(s[r], -80.f), 80.f) * SC2 - CL2;
        if (diag) {
          const int kpos = k0 + j * 16 + quad * 4 + r;
          if (kpos > qpos) t = -12000.f;
        }
        float p = exp2f(t);
        ps[j][r] = p;
        lpart += p;
      }
    }
    __builtin_amdgcn_s_setprio(0);

    short8 Pb0, Pb1;
#pragma unroll
    for (int i = 0; i < 4; i++) {
      Pb0[i]     = f2bf(ps[0][i]);
      Pb0[i + 4] = f2bf(ps[1][i]);
      Pb1[i]     = f2bf(ps[2][i]);
      Pb1[i + 4] = f2bf(ps[3][i]);
    }
    __builtin_amdgcn_s_setprio(1);
#pragma unroll
    for (int c = 0; c < 4; c++) {
      const short* vrow = &Vt[c * 16 + l15][0];
      short8 a0 = *(const short8*)&vrow[quad * 8];
      short8 a1 = *(const short8*)&vrow[32 + quad * 8];
      accO[c] = __builtin_amdgcn_mfma_f32_16x16x32_bf16(a0, Pb0, accO[c], 0, 0, 0);
      accO[c] = __builtin_amdgcn_mfma_f32_16x16x32_bf16(a1, Pb1, accO[c], 0, 0, 0);
    }
    __builtin_amdgcn_s_setprio(0);
  }

  float rs = lpart;
  rs += __shfl_xor(rs, 16);
  rs += __shfl_xor(rs, 32);
  float inv = (rs > 0.f) ? 1.f / rs : 0.f;
  const size_t obase = (size_t)qpos * 1024 + head * 64;
#pragma unroll
  for (int c = 0; c < 4; c++) {
    short4v o;
#pragma unroll
    for (int r = 0; r < 4; r++) o[r] = f2bf(accO[c][r] * inv);
    *(short4v*)&Ob[obase + c * 16 + quad * 4] = o;
  }
}

extern "C" void kernel_launch(void* const* d_in, const int* in_sizes, int n_in,
                              void* d_out, int out_size, void* d_ws, size_t ws_size,
                              hipStream_t stream) {
  const void* x     = d_in[0];
  const void* W_DQ  = d_in[1];
  const void* W_UQ  = d_in[2];
  const void* W_QR  = d_in[3];
  const void* W_DKV = d_in[4];
  const void* W_UK  = d_in[5];
  const void* W_UV  = d_in[6];
  const void* W_KR  = d_in[7];
  const void* W_O   = d_in[8];
  float* out = (float*)d_out;
  __hip_bfloat16* ws = (__hip_bfloat16*)d_ws;

  dim3 blk(256);

  if (ws_size >= (size_t)76021760) {
    // ---------- big path ----------
    __hip_bfloat16* cQ   = ws;                 // 8192x512
    __hip_bfloat16* cKV  = ws + 4194304;       // 8192x512
    __hip_bfloat16* attn = ws;                 // 8192x1024 (overlays dead cQ+cKV)
    __hip_bfloat16* qC   = ws + 8388608;       // (B,S,H,64)
    __hip_bfloat16* qR   = ws + 16777216;      // (B,S,H,32)
    __hip_bfloat16* kC   = ws + 20971520;      // (B,S,H,64)
    __hip_bfloat16* vT   = ws + 29360128;      // (B,1024,2048)
    __hip_bfloat16* kR   = ws + 37748736;      // (B,S,32)

    // bf16 scratch inside d_out (dead until final GEMM overwrites it):
    short* xb   = (short*)out;                 // 8,388,608 el (x as bf16)
    short* wb   = xb + 8388608;                // packed weights
    short* wDQ  = wb;                          // 524288
    short* wDKV = wb + 524288;                 // 524288
    short* wUQ  = wb + 1048576;                // 524288
    short* wQR  = wb + 1572864;                // 262144
    short* wUK  = wb + 1835008;                // 524288
    short* wUV  = wb + 2359296;                // 524288
    short* wKR  = wb + 2883584;                // 32768
    short* wO   = (short*)qC;                  // W_O bf16, written AFTER attn (qC dead)

    cvt_all<<<dim3(5520), blk, 0, stream>>>((const float*)x, (const float*)W_DQ,
        (const float*)W_DKV, (const float*)W_UQ, (const float*)W_QR,
        (const float*)W_UK, (const float*)W_UV, (const float*)W_KR, xb);

    // Down-proj + KR: 3 segments sharing A=xb, one launch (9x64 = 576 blocks).
    gemm128_multi<<<dim3(9, 64), blk, 0, stream>>>(
        xb, wDQ,  cQ, 512, 0, 4, 512,
        xb, wDKV, cKV, 512, 0, 4, 512,
        xb, wKR,  kR,  32, 0, 1, 32,
        xb, wKR,  kR,  32, 0, 32,      // unreachable dummy
        1024);
    // All four up-proj GEMMs: one launch (28x64 = 1792 blocks ~ 5 blocks/CU).
    gemm128_multi<<<dim3(28, 64), blk, 0, stream>>>(
        (short*)cQ,  wUQ, qC, 1024, 0, 8, 1024,
        (short*)cQ,  wQR, qR,  512, 0, 4, 512,
        (short*)cKV, wUK, kC, 1024, 0, 8, 1024,
        (short*)cKV, wUV, vT, 1024, 1, 1024,
        512);
    rope_kernel<<<dim3(8192), blk, 0, stream>>>(qR, 2097152, 256);
    rope_kernel<<<dim3(512), blk, 0, stream>>>(kR, 131072, 16);
    mla_attn<<<dim3(32, 16, 4), blk, 0, stream>>>(qC, qR, kC, kR, vT, attn);
    cvt_f32_bf16<<<dim3(512), blk, 0, stream>>>((const float*)W_O, wO, 131072);
    gemm128<<<dim3(8, 64), blk, 0, stream>>>((short*)attn, wO, out, 8192, 1024, 1024, 2);
  } else {
    // ---------- small path: per-batch arena (unchanged fallback) ----------
    __hip_bfloat16* qc = ws;
    __hip_bfloat16* qr = ws + 2097152;
    __hip_bfloat16* kc = ws + 3145728;
    __hip_bfloat16* kr = ws + 5242880;
    __hip_bfloat16* F  = ws + 5308416;

    for (int b = 0; b < 4; b++) {
      unsigned long long xoff = (unsigned long long)b * 2048 * 1024;
      float* outb = out + (size_t)b * 2097152;
      __hip_bfloat16* vtb = (__hip_bfloat16*)outb;

      gemm_bt<<<dim3(8, 32), blk, 0, stream>>>(x, W_DQ,  F,  2048, 512, 1024, 0, 1, 1, xoff);
      gemm_bt<<<dim3(16, 32), blk, 0, stream>>>(F, W_UQ,  qc, 2048, 1024, 512, 0, 0, 1, 0);
      gemm_bt<<<dim3(8, 32), blk, 0, stream>>>(F, W_QR,  qr, 2048, 512, 512, 0, 0, 1, 0);
      gemm_bt<<<dim3(8, 32), blk, 0, stream>>>(x, W_DKV, F,  2048, 512, 1024, 0, 1, 1, xoff);
      gemm_bt<<<dim3(16, 32), blk, 0, stream>>>(F, W_UK,  kc, 2048, 1024, 512, 0, 0, 1, 0);
      gemm_bt<<<dim3(16, 32), blk, 0, stream>>>(F, W_UV,  vtb, 2048, 1024, 512, 1, 0, 1, 0);
      gemm_bt<<<dim3(1, 32), blk, 0, stream>>>(x, W_KR,  kr, 2048, 32, 1024, 0, 1, 1, xoff);
      rope_kernel<<<dim3(2048), blk, 0, stream>>>(qr, 524288, 256);
      rope_kernel<<<dim3(128), blk, 0, stream>>>(kr, 32768, 16);
      mla_attn<<<dim3(32, 16, 1), blk, 0, stream>>>(qc, qr, kc, kr, vtb, F);
      gemm_bt<<<dim3(16, 32), blk, 0, stream>>>(F, W_O, outb, 2048, 1024, 1024, 2, 0, 1, 0);
    }
  }
}